// Round 15
// baseline (189.426 us; speedup 1.0000x reference)
//
#include <hip/hip_runtime.h>

#define Nn 4096
#define Mm 4096
#define Dd 512
#define Ee 128
#define KOUT 256
#define NBINS 4096
#define CAP 4096

// ---- workspace layout (bytes) ----
#define ROWSUM_OFF 0
#define COLSUM_OFF 16384
#define REN2_OFF   32768
#define SEN2_OFF   49152
#define HIST_OFF   65536
#define SCAN_OFF   81920            // fallback path only
#define CNT_OFF    81928            // [0]=cand count
#define CANDV_OFF  98304
#define CANDI_OFF  114688
// partials [4096][32] f32
#define RP32_OFF   131072
#define CP32_OFF   655360
// reciprocal sums (main path)
#define RINV_OFF   1179648
#define CINV_OFF   1196032          // ends 1212416
// old fallback partials [4096][64]
#define ROWPART_OFF 131072
#define COLPART_OFF (131072 + 1048576)
// bf16 split arrays, staging-tiled layout: each 4096*640*2 = 5 MB
#define AH_OFF   4194304
#define AL_OFF   (AH_OFF + 5242880)
#define BH_OFF   (AL_OFF + 5242880)
#define BL_OFF   (BH_OFF + 5242880)
#define SNEW_OFF 25165824            // bf16 S: 32 MB -> ends 56 MB
#define NEW_REQ  ((size_t)SNEW_OFF + (size_t)Nn * Mm * 2)
// old fallback S at 4 MB (f32)
#define S_OFF      4194304
#define FAST_REQ   ((size_t)S_OFF + (size_t)Nn * Mm * 4)

typedef float f32x16 __attribute__((ext_vector_type(16)));
typedef float f32x4 __attribute__((ext_vector_type(4)));
typedef __bf16 bf16x8 __attribute__((ext_vector_type(8)));

// fused zero + norms (fallback paths only)
__global__ __launch_bounds__(64)
void setup_kernel(const float* __restrict__ re, const float* __restrict__ se,
                  float* __restrict__ ws) {
    int row = blockIdx.x;
    int t = threadIdx.x;
    int g4 = row * 64 + t;
    if (g4 < NBINS + 8) ((unsigned*)ws)[HIST_OFF / 4 + g4] = 0;
    const float* p = (row < Nn) ? (re + (size_t)row * Ee) : (se + (size_t)(row - Nn) * Ee);
    float x0 = p[t], x1 = p[t + 64];
    float v = x0 * x0 + x1 * x1;
    #pragma unroll
    for (int o = 32; o > 0; o >>= 1) v += __shfl_down(v, o);
    if (t == 0) {
        if (row < Nn) ws[REN2_OFF / 4 + row] = v;
        else          ws[SEN2_OFF / 4 + row - Nn] = v;
    }
}

// ---------------- MFMA path ----------------

__device__ __forceinline__ unsigned short b16rtn(float x) {
    unsigned u = __float_as_uint(x);
    return (unsigned short)((u + 0x7fffu + ((u >> 16) & 1u)) >> 16);
}
__device__ __forceinline__ void split1(float x, unsigned short& h, unsigned short& l) {
    h = b16rtn(x);
    float hf = __uint_as_float((unsigned)h << 16);
    l = b16rtn(x - hf);
}

// prep v2: tile-transposed, fully coalesced (proven R10). Zeroes hist/counter,
// computes equ norms.
__global__ __launch_bounds__(256)
void prep_kernel(const float* __restrict__ rf, const float* __restrict__ sf,
                 const float* __restrict__ re, const float* __restrict__ se,
                 unsigned short* __restrict__ AH, unsigned short* __restrict__ AL,
                 unsigned short* __restrict__ BH, unsigned short* __restrict__ BL,
                 float* __restrict__ ws) {
    __shared__ unsigned short ldsT[4][4][128][8];   // 32 KB
    const int tid = threadIdx.x;
    const int gt = blockIdx.x * 256 + tid;
    if (gt < NBINS + 8) ((unsigned*)ws)[HIST_OFF / 4 + gt] = 0;

    const int p = blockIdx.x / 20;
    const int t = blockIdx.x % 20;
    const int rowbase = p * 128;
    const bool equ = (t >= 16);
    const float* srcA = equ ? re : rf;
    const float* srcB = equ ? se : sf;
    const int stride = equ ? Ee : Dd;
    const int kcol = equ ? (t * 32 - Dd) : (t * 32);
    const float bscale = equ ? 0.1f : 1.0f;

    const int rl = tid >> 1;
    const int half = tid & 1;
    const float4* ra = (const float4*)(srcA + (size_t)(rowbase + rl) * stride + kcol + half * 16);
    const float4* rb = (const float4*)(srcB + (size_t)(rowbase + rl) * stride + kcol + half * 16);
    #pragma unroll
    for (int v4 = 0; v4 < 4; ++v4) {
        float4 a = ra[v4];
        float4 b = rb[v4];
        float av[4] = {a.x, a.y, a.z, a.w};
        float bv[4] = {b.x, b.y, b.z, b.w};
        #pragma unroll
        for (int q = 0; q < 4; ++q) {
            int kl = half * 16 + v4 * 4 + q;
            int g = kl >> 3, e = kl & 7;
            unsigned short h, l;
            split1(av[q], h, l);
            ldsT[0][g][rl][e] = h;
            ldsT[1][g][rl][e] = l;
            split1(bscale * bv[q], h, l);
            ldsT[2][g][rl][e] = h;
            ldsT[3][g][rl][e] = l;
        }
    }
    __syncthreads();
    const size_t tile = ((size_t)p * 20 + t) * 4096;
    {
        const uint4* s0 = (const uint4*)&ldsT[0][0][0][0];
        const uint4* s1 = (const uint4*)&ldsT[1][0][0][0];
        const uint4* s2 = (const uint4*)&ldsT[2][0][0][0];
        const uint4* s3 = (const uint4*)&ldsT[3][0][0][0];
        uint4* d0 = (uint4*)(AH + tile);
        uint4* d1 = (uint4*)(AL + tile);
        uint4* d2 = (uint4*)(BH + tile);
        uint4* d3 = (uint4*)(BL + tile);
        d0[tid * 2] = s0[tid * 2]; d0[tid * 2 + 1] = s0[tid * 2 + 1];
        d1[tid * 2] = s1[tid * 2]; d1[tid * 2 + 1] = s1[tid * 2 + 1];
        d2[tid * 2] = s2[tid * 2]; d2[tid * 2 + 1] = s2[tid * 2 + 1];
        d3[tid * 2] = s3[tid * 2]; d3[tid * 2 + 1] = s3[tid * 2 + 1];
    }

    if (blockIdx.x < 512) {
        int w = (tid >> 6);
        int lane = tid & 63;
        #pragma unroll
        for (int i = 0; i < 4; ++i) {
            int row = blockIdx.x * 16 + w * 4 + i;
            const float* pr = (row < Nn) ? (re + (size_t)row * Ee)
                                         : (se + (size_t)(row - Nn) * Ee);
            float x0 = pr[lane], x1 = pr[lane + 64];
            float v = x0 * x0 + x1 * x1;
            #pragma unroll
            for (int o = 32; o > 0; o >>= 1) v += __shfl_down(v, o);
            if (lane == 0) {
                if (row < Nn) ws[REN2_OFF / 4 + row] = v;
                else          ws[SEN2_OFF / 4 + row - Nn] = v;
            }
        }
    }
}

__device__ __forceinline__ void gload16(const void* g, void* l) {
    __builtin_amdgcn_global_load_lds((const __attribute__((address_space(1))) unsigned*)g,
                                     (__attribute__((address_space(3))) unsigned*)l, 16, 0, 0);
}

// Logical K = 1920: kt in [0,20) -> AH.BH, [20,40) -> AL.BH, [40,60) -> AH.BL.
// 32x32x16 MFMA: wave computes 64x64 as 2x2 blocks of 32x32.
// C/D layout: col = lane&31, row = (reg&3)+8*(reg>>2)+4*(lane>>5).
// Exact f32 row/col partial sums from registers; S stored as bf16.
__global__ __launch_bounds__(256, 4)
void mfma_gemm_kernel(const __bf16* __restrict__ AH, const __bf16* __restrict__ AL,
                      const __bf16* __restrict__ BH, const __bf16* __restrict__ BL,
                      float* __restrict__ ws, unsigned short* __restrict__ S) {
    __shared__ __bf16 lds[2][2][4096];   // [dbuf][A/B][g*1024 + r*8 + e] = 32 KB
    const int tid = threadIdx.x;
    const int lane = tid & 63, wid = tid >> 6;
    const int bx = blockIdx.x, by = blockIdx.y;
    const int rowbase = by * 128, colbase = bx * 128;
    const int wr = wid >> 1, wc = wid & 1;
    const int l31 = lane & 31, h = lane >> 5;

    f32x16 acc[2][2];
    #pragma unroll
    for (int i = 0; i < 2; ++i)
        #pragma unroll
        for (int j = 0; j < 2; ++j)
            #pragma unroll
            for (int q = 0; q < 16; ++q) acc[i][j][q] = 0.f;

    auto stage = [&](int buf, int kt) {
        const int seg = (kt >= 40) ? 2 : (kt >= 20) ? 1 : 0;
        const int t = kt - seg * 20;
        const __bf16* asrc = (seg == 1) ? AL : AH;
        const __bf16* bsrc = (seg == 2) ? BL : BH;
        const __bf16* pa = asrc + ((size_t)by * 20 + t) * 4096;
        const __bf16* pb = bsrc + ((size_t)bx * 20 + t) * 4096;
        #pragma unroll
        for (int q = 0; q < 4; ++q) {
            int flat = wid * 4 + q;
            int arr = flat >> 3;
            int chunk = flat & 7;
            const __bf16* s = (arr ? pb : pa) + chunk * 512 + lane * 8;
            gload16(s, (void*)&lds[buf][arr][chunk * 512]);
        }
    };

    stage(0, 0);
    for (int kt = 0; kt < 60; ++kt) {
        const int buf = kt & 1;
        __syncthreads();
        if (kt + 1 < 60) stage(buf ^ 1, kt + 1);
        const __bf16* Asl = &lds[buf][0][0];
        const __bf16* Bsl = &lds[buf][1][0];
        // A-frag (32x32x16): lane reads row=l31, k = kh*16 + 8*h + e  -> g = kh*2 + h
        bf16x8 a[2][2], b[2][2];
        #pragma unroll
        for (int bi = 0; bi < 2; ++bi)
            #pragma unroll
            for (int kh = 0; kh < 2; ++kh) {
                int g = kh * 2 + h;
                a[bi][kh] = *(const bf16x8*)&Asl[(g * 128 + wr * 64 + bi * 32 + l31) * 8];
                b[bi][kh] = *(const bf16x8*)&Bsl[(g * 128 + wc * 64 + bi * 32 + l31) * 8];
            }
        #pragma unroll
        for (int bi = 0; bi < 2; ++bi)
            #pragma unroll
            for (int bj = 0; bj < 2; ++bj) {
                acc[bi][bj] = __builtin_amdgcn_mfma_f32_32x32x16_bf16(a[bi][0], b[bj][0], acc[bi][bj], 0, 0, 0);
                acc[bi][bj] = __builtin_amdgcn_mfma_f32_32x32x16_bf16(a[bi][1], b[bj][1], acc[bi][bj], 0, 0, 0);
            }
    }
    __syncthreads();

    // epilogue
    float sen2v[2];
    #pragma unroll
    for (int bj = 0; bj < 2; ++bj)
        sen2v[bj] = ws[SEN2_OFF / 4 + colbase + wc * 64 + bj * 32 + l31];

    float* red = (float*)&lds[0][0][0];
    float colacc[2] = {0.f, 0.f};
    #pragma unroll
    for (int bi = 0; bi < 2; ++bi) {
        float ren2v[16], rowacc[16];
        #pragma unroll
        for (int r = 0; r < 16; ++r) {
            ren2v[r] = ws[REN2_OFF / 4 + rowbase + wr * 64 + bi * 32 + ((r & 3) + 8 * (r >> 2) + 4 * h)];
            rowacc[r] = 0.f;
        }
        #pragma unroll
        for (int bj = 0; bj < 2; ++bj)
            #pragma unroll
            for (int r = 0; r < 16; ++r) {
                float e = acc[bi][bj][r] - 0.05f * (ren2v[r] + sen2v[bj]) - 1.0f;
                float s = expf(e);
                acc[bi][bj][r] = s;
                rowacc[r] += s;
                colacc[bj] += s;
            }
        #pragma unroll
        for (int r = 0; r < 16; ++r) {
            float vv = rowacc[r];
            vv += __shfl_xor(vv, 1); vv += __shfl_xor(vv, 2);
            vv += __shfl_xor(vv, 4); vv += __shfl_xor(vv, 8);
            vv += __shfl_xor(vv, 16);
            if (l31 == 0)
                red[wc * 128 + wr * 64 + bi * 32 + ((r & 3) + 8 * (r >> 2) + 4 * h)] = vv;
        }
    }
    #pragma unroll
    for (int bj = 0; bj < 2; ++bj) {
        float vv = colacc[bj];
        vv += __shfl_xor(vv, 32);
        if (h == 0) red[256 + wr * 128 + wc * 64 + bj * 32 + l31] = vv;
    }

    // S as bf16
    #pragma unroll
    for (int bi = 0; bi < 2; ++bi)
        #pragma unroll
        for (int r = 0; r < 16; ++r) {
            int rw = rowbase + wr * 64 + bi * 32 + ((r & 3) + 8 * (r >> 2) + 4 * h);
            #pragma unroll
            for (int bj = 0; bj < 2; ++bj) {
                int cc = colbase + wc * 64 + bj * 32 + l31;
                S[(size_t)rw * Mm + cc] = b16rtn(acc[bi][bj][r]);
            }
        }

    __syncthreads();
    if (tid < 128) {
        ws[RP32_OFF / 4 + (size_t)(rowbase + tid) * 32 + bx] = red[tid] + red[128 + tid];
    } else {
        int t2 = tid - 128;
        ws[CP32_OFF / 4 + (size_t)(colbase + t2) * 32 + by] = red[256 + t2] + red[384 + t2];
    }
}

__global__ __launch_bounds__(256)
void partred32_kernel(float* __restrict__ w) {
    int i = blockIdx.x * 256 + threadIdx.x;   // [0, 8192)
    const float* p = (i < Nn) ? (w + RP32_OFF / 4 + (size_t)i * 32)
                              : (w + CP32_OFF / 4 + (size_t)(i - Nn) * 32);
    float a = 0.f;
    #pragma unroll
    for (int k = 0; k < 32; ++k) a += p[k];
    if (i < Nn) { w[ROWSUM_OFF / 4 + i] = a; w[RINV_OFF / 4 + i] = 1.0f / a; }
    else        { w[COLSUM_OFF / 4 + i - Nn] = a; w[CINV_OFF / 4 + i - Nn] = 1.0f / a; }
}

// ---------------- selection pipeline (bf16 map + margin + exact rescore) ----------------

__global__ __launch_bounds__(256)
void histb_kernel(const unsigned short* __restrict__ S, float* __restrict__ ws) {
    __shared__ unsigned lh[NBINS];
    for (int b = threadIdx.x; b < NBINS; b += 256) lh[b] = 0;
    __syncthreads();
    const float* rinv = ws + RINV_OFF / 4;
    const float* cinv = ws + CINV_OFF / 4;
    unsigned* hist = (unsigned*)ws + HIST_OFF / 4;
    const uint4* S8 = (const uint4*)S;
    int gtid = blockIdx.x * 256 + threadIdx.x;
    const int total8 = Nn * Mm / 8;
    for (int idx = gtid; idx < total8; idx += gridDim.x * 256) {
        uint4 v = S8[idx];
        int lin = idx * 8;
        int i = lin >> 12, j = lin & 4095;
        float ri = rinv[i];
        float4 c0 = *(const float4*)&cinv[j];
        float4 c1 = *(const float4*)&cinv[j + 4];
        unsigned uu[4] = {v.x, v.y, v.z, v.w};
        float cs[8] = {c0.x, c0.y, c0.z, c0.w, c1.x, c1.y, c1.z, c1.w};
        #pragma unroll
        for (int q = 0; q < 4; ++q) {
            float s0 = __uint_as_float((uu[q] & 0xffffu) << 16);
            float s1 = __uint_as_float((uu[q] >> 16) << 16);
            float f0 = (s0 * ri) * (s0 * cs[q * 2]);
            float f1 = (s1 * ri) * (s1 * cs[q * 2 + 1]);
            atomicAdd(&lh[__float_as_uint(f0) >> 20], 1u);
            atomicAdd(&lh[__float_as_uint(f1) >> 20], 1u);
        }
    }
    __syncthreads();
    for (int b = threadIdx.x; b < NBINS; b += 256) {
        unsigned c = lh[b];
        if (c) atomicAdd(&hist[b], c);
    }
}

// compact with replicated scan head; tau lowered by 1.5e-2 relative margin.
__global__ __launch_bounds__(256)
void compactb_kernel(const unsigned short* __restrict__ S, float* __restrict__ ws) {
    __shared__ unsigned lh[NBINS];
    __shared__ unsigned tauS;
    unsigned* ghist = (unsigned*)ws + HIST_OFF / 4;
    int t = threadIdx.x;
    for (int i = t; i < NBINS; i += 256) lh[i] = ghist[NBINS - 1 - i];
    __syncthreads();
    for (int st = 1; st < NBINS; st <<= 1) {
        unsigned tv[16];
        #pragma unroll
        for (int q = 0; q < 16; ++q) {
            int i = q * 256 + t;
            tv[q] = lh[i] + (i >= st ? lh[i - st] : 0u);
        }
        __syncthreads();
        #pragma unroll
        for (int q = 0; q < 16; ++q) lh[q * 256 + t] = tv[q];
        __syncthreads();
    }
    for (int i = t; i < NBINS; i += 256) {
        if (lh[i] >= KOUT && (i == 0 || lh[i - 1] < KOUT))
            tauS = (unsigned)(NBINS - 1 - i) << 20;
    }
    __syncthreads();
    const float tauf = __uint_as_float(tauS) * (1.0f - 1.5e-2f);

    const float* rinv = ws + RINV_OFF / 4;
    const float* cinv = ws + CINV_OFF / 4;
    int* counter = (int*)ws + CNT_OFF / 4;
    float* candv = ws + CANDV_OFF / 4;
    int* candi = (int*)ws + CANDI_OFF / 4;
    const uint4* S8 = (const uint4*)S;
    int gtid = blockIdx.x * 256 + threadIdx.x;
    const int total8 = Nn * Mm / 8;
    for (int idx = gtid; idx < total8; idx += gridDim.x * 256) {
        uint4 v = S8[idx];
        int lin = idx * 8;
        int i = lin >> 12, j = lin & 4095;
        float ri = rinv[i];
        float4 c0 = *(const float4*)&cinv[j];
        float4 c1 = *(const float4*)&cinv[j + 4];
        unsigned uu[4] = {v.x, v.y, v.z, v.w};
        float cs[8] = {c0.x, c0.y, c0.z, c0.w, c1.x, c1.y, c1.z, c1.w};
        #pragma unroll
        for (int q = 0; q < 8; ++q) {
            unsigned hw = (q & 1) ? (uu[q >> 1] >> 16) : (uu[q >> 1] & 0xffffu);
            float s = __uint_as_float(hw << 16);
            float f = (s * ri) * (s * cs[q]);
            if (f >= tauf) {
                int p = atomicAdd(counter, 1);
                if (p < CAP) {
                    candv[p] = f;
                    candi[p] = lin + q;
                }
            }
        }
    }
}

// fused exact rescore + bitonic select (single block, 1024 threads = 16 waves)
__global__ __launch_bounds__(1024)
void rescore_select_kernel(const float* __restrict__ rf, const float* __restrict__ sf,
                           const float* __restrict__ re, const float* __restrict__ se,
                           const float* __restrict__ ws, float* __restrict__ out) {
    __shared__ float v[CAP];
    __shared__ int id[CAP];
    const int* counter = (const int*)ws + CNT_OFF / 4;
    const int* candi = (const int*)ws + CANDI_OFF / 4;
    int n = *counter;
    if (n > CAP) n = CAP;
    int P = 256;
    while (P < n) P <<= 1;
    const int t = threadIdx.x;
    for (int i = t; i < P; i += 1024) { v[i] = -1.0f; id[i] = 0x7fffffff; }
    __syncthreads();

    const int wv = t >> 6, lane = t & 63;
    for (int cid = wv; cid < n; cid += 16) {
        const int idx = candi[cid];
        const int r = idx >> 12, c = idx & (Mm - 1);
        float d1 = 0.f, d2 = 0.f;
        const float* ar = rf + (size_t)r * Dd;
        const float* bc = sf + (size_t)c * Dd;
        #pragma unroll
        for (int k = 0; k < 8; ++k) d1 = fmaf(ar[lane + k * 64], bc[lane + k * 64], d1);
        const float* er = re + (size_t)r * Ee;
        const float* ec = se + (size_t)c * Ee;
        #pragma unroll
        for (int k = 0; k < 2; ++k) d2 = fmaf(er[lane + k * 64], ec[lane + k * 64], d2);
        #pragma unroll
        for (int o = 32; o > 0; o >>= 1) {
            d1 += __shfl_xor(d1, o);
            d2 += __shfl_xor(d2, o);
        }
        if (lane == 0) {
            float rn = ws[REN2_OFF / 4 + r], cn = ws[SEN2_OFF / 4 + c];
            float e1 = fmaxf(2.0f - 2.0f * d1, 0.0f);
            float e2 = fmaxf(rn + cn - 2.0f * d2, 0.0f);
            float s = expf(-(0.5f * e1 + 0.05f * e2));
            float R = ws[ROWSUM_OFF / 4 + r], C = ws[COLSUM_OFF / 4 + c];
            v[cid] = (s / R) * (s / C);
            id[cid] = idx;
        }
    }
    __syncthreads();

    for (int k = 2; k <= P; k <<= 1) {
        for (int j = k >> 1; j > 0; j >>= 1) {
            for (int i = t; i < P; i += 1024) {
                int ixj = i ^ j;
                if (ixj > i) {
                    float va = v[i], vb = v[ixj];
                    int ia = id[i], ib = id[ixj];
                    bool aFirst = (va > vb) || (va == vb && ia < ib);
                    bool up = ((i & k) == 0);
                    if (up ? !aFirst : aFirst) {
                        v[i] = vb; v[ixj] = va;
                        id[i] = ib; id[ixj] = ia;
                    }
                }
            }
            __syncthreads();
        }
    }
    if (t < KOUT) {
        int idx = id[t];
        out[t]            = (float)(idx >> 12);
        out[KOUT + t]     = (float)(idx & (Mm - 1));
        out[2 * KOUT + t] = v[t];
    }
}

__global__ __launch_bounds__(1024)
void select_kernel(const float* __restrict__ ws, float* __restrict__ out) {
    const int* counter = (const int*)ws + CNT_OFF / 4;
    const float* candv = ws + CANDV_OFF / 4;
    const int* candi = (const int*)ws + CANDI_OFF / 4;
    int n = *counter;
    if (n > CAP) n = CAP;
    int P = 256;
    while (P < n) P <<= 1;
    __shared__ float v[CAP];
    __shared__ int id[CAP];
    int t = threadIdx.x;
    for (int i = t; i < P; i += 1024) {
        if (i < n) { v[i] = candv[i]; id[i] = candi[i]; }
        else       { v[i] = -1.0f;    id[i] = 0x7fffffff; }
    }
    __syncthreads();
    for (int k = 2; k <= P; k <<= 1) {
        for (int j = k >> 1; j > 0; j >>= 1) {
            for (int i = t; i < P; i += 1024) {
                int ixj = i ^ j;
                if (ixj > i) {
                    float va = v[i], vb = v[ixj];
                    int ia = id[i], ib = id[ixj];
                    bool aFirst = (va > vb) || (va == vb && ia < ib);
                    bool up = ((i & k) == 0);
                    if (up ? !aFirst : aFirst) {
                        v[i] = vb; v[ixj] = va;
                        id[i] = ib; id[ixj] = ia;
                    }
                }
            }
            __syncthreads();
        }
    }
    if (t < KOUT) {
        int idx = id[t];
        out[t]            = (float)(idx >> 12);
        out[KOUT + t]     = (float)(idx & (Mm - 1));
        out[2 * KOUT + t] = v[t];
    }
}

// ---------------- old f32 fallback path (proven R2) ----------------

template <int MODE>
__global__ __launch_bounds__(256)
void tile_kernel(const float* __restrict__ rf, const float* __restrict__ sf,
                 const float* __restrict__ re, const float* __restrict__ se,
                 float* __restrict__ ws) {
    const int bx = blockIdx.x, by = blockIdx.y;
    const int tid = threadIdx.x;
    const int tx = tid & 15, ty = tid >> 4;
    const int rowbase = by * 64, colbase = bx * 64;

    __shared__ float As[16][68];
    __shared__ float Bs[16][68];

    float acc1[4][4] = {};
    float acc2[4][4] = {};

    for (int kk = 0; kk < Dd; kk += 16) {
        #pragma unroll
        for (int i = 0; i < 4; ++i) {
            int f = tid + i * 256;
            int r = f >> 4, c = f & 15;
            As[c][r] = rf[(size_t)(rowbase + r) * Dd + kk + c];
            Bs[c][r] = sf[(size_t)(colbase + r) * Dd + kk + c];
        }
        __syncthreads();
        #pragma unroll
        for (int k = 0; k < 16; ++k) {
            float a[4], b[4];
            #pragma unroll
            for (int i = 0; i < 4; ++i) a[i] = As[k][ty * 4 + i];
            #pragma unroll
            for (int j = 0; j < 4; ++j) b[j] = Bs[k][tx * 4 + j];
            #pragma unroll
            for (int i = 0; i < 4; ++i)
                #pragma unroll
                for (int j = 0; j < 4; ++j)
                    acc1[i][j] = fmaf(a[i], b[j], acc1[i][j]);
        }
        __syncthreads();
    }
    for (int kk = 0; kk < Ee; kk += 16) {
        #pragma unroll
        for (int i = 0; i < 4; ++i) {
            int f = tid + i * 256;
            int r = f >> 4, c = f & 15;
            As[c][r] = re[(size_t)(rowbase + r) * Ee + kk + c];
            Bs[c][r] = se[(size_t)(colbase + r) * Ee + kk + c];
        }
        __syncthreads();
        #pragma unroll
        for (int k = 0; k < 16; ++k) {
            float a[4], b[4];
            #pragma unroll
            for (int i = 0; i < 4; ++i) a[i] = As[k][ty * 4 + i];
            #pragma unroll
            for (int j = 0; j < 4; ++j) b[j] = Bs[k][tx * 4 + j];
            #pragma unroll
            for (int i = 0; i < 4; ++i)
                #pragma unroll
                for (int j = 0; j < 4; ++j)
                    acc2[i][j] = fmaf(a[i], b[j], acc2[i][j]);
        }
        __syncthreads();
    }

    const int r0 = rowbase + ty * 4, c0 = colbase + tx * 4;
    float rn[4], cn[4];
    #pragma unroll
    for (int i = 0; i < 4; ++i) rn[i] = ws[REN2_OFF / 4 + r0 + i];
    #pragma unroll
    for (int j = 0; j < 4; ++j) cn[j] = ws[SEN2_OFF / 4 + c0 + j];

    float s[4][4];
    #pragma unroll
    for (int i = 0; i < 4; ++i)
        #pragma unroll
        for (int j = 0; j < 4; ++j) {
            float d1 = fmaxf(2.0f - 2.0f * acc1[i][j], 0.0f);
            float sq = fmaxf(rn[i] + cn[j] - 2.0f * acc2[i][j], 0.0f);
            s[i][j] = expf(-(0.5f * d1 + 0.05f * sq));
        }

    if constexpr (MODE == 0) {
        float* S = ws + S_OFF / 4;
        #pragma unroll
        for (int i = 0; i < 4; ++i) {
            float4 v = make_float4(s[i][0], s[i][1], s[i][2], s[i][3]);
            *(float4*)&S[(size_t)(r0 + i) * Mm + c0] = v;
        }
    }
    if constexpr (MODE == 1) {
        __shared__ float red[64][17];
        #pragma unroll
        for (int i = 0; i < 4; ++i)
            red[ty * 4 + i][tx] = s[i][0] + s[i][1] + s[i][2] + s[i][3];
        __syncthreads();
        if (tid < 64) {
            float t = 0.f;
            #pragma unroll
            for (int k = 0; k < 16; ++k) t += red[tid][k];
            ws[ROWPART_OFF / 4 + (size_t)(rowbase + tid) * 64 + bx] = t;
        }
        __syncthreads();
        #pragma unroll
        for (int j = 0; j < 4; ++j)
            red[tx * 4 + j][ty] = s[0][j] + s[1][j] + s[2][j] + s[3][j];
        __syncthreads();
        if (tid < 64) {
            float t = 0.f;
            #pragma unroll
            for (int k = 0; k < 16; ++k) t += red[tid][k];
            ws[COLPART_OFF / 4 + (size_t)(colbase + tid) * 64 + by] = t;
        }
    }
    if constexpr (MODE == 2) {
        __shared__ unsigned lh[NBINS];
        for (int b = tid; b < NBINS; b += 256) lh[b] = 0;
        __syncthreads();
        float rs[4], cs[4];
        #pragma unroll
        for (int i = 0; i < 4; ++i) rs[i] = ws[ROWSUM_OFF / 4 + r0 + i];
        #pragma unroll
        for (int j = 0; j < 4; ++j) cs[j] = ws[COLSUM_OFF / 4 + c0 + j];
        #pragma unroll
        for (int i = 0; i < 4; ++i)
            #pragma unroll
            for (int j = 0; j < 4; ++j) {
                float f = (s[i][j] / rs[i]) * (s[i][j] / cs[j]);
                atomicAdd(&lh[__float_as_uint(f) >> 20], 1u);
            }
        __syncthreads();
        unsigned* hist = (unsigned*)ws + HIST_OFF / 4;
        for (int b = tid; b < NBINS; b += 256) {
            unsigned cc = lh[b];
            if (cc) atomicAdd(&hist[b], cc);
        }
    }
    if constexpr (MODE == 3) {
        unsigned tau = ((unsigned*)ws)[SCAN_OFF / 4];
        int* counter = (int*)ws + CNT_OFF / 4;
        float* candv = ws + CANDV_OFF / 4;
        int* candi = (int*)ws + CANDI_OFF / 4;
        float rs[4], cs[4];
        #pragma unroll
        for (int i = 0; i < 4; ++i) rs[i] = ws[ROWSUM_OFF / 4 + r0 + i];
        #pragma unroll
        for (int j = 0; j < 4; ++j) cs[j] = ws[COLSUM_OFF / 4 + c0 + j];
        #pragma unroll
        for (int i = 0; i < 4; ++i)
            #pragma unroll
            for (int j = 0; j < 4; ++j) {
                float f = (s[i][j] / rs[i]) * (s[i][j] / cs[j]);
                if (__float_as_uint(f) >= tau) {
                    int p = atomicAdd(counter, 1);
                    if (p < CAP) {
                        candv[p] = f;
                        candi[p] = (r0 + i) * Mm + (c0 + j);
                    }
                }
            }
    }
}

__global__ __launch_bounds__(256)
void partred_kernel(float* __restrict__ w) {
    int i = blockIdx.x * 256 + threadIdx.x;
    const float* rp = w + ROWPART_OFF / 4 + (size_t)i * 64;
    const float* cp = w + COLPART_OFF / 4 + (size_t)i * 64;
    float a = 0.f, b = 0.f;
    #pragma unroll
    for (int k = 0; k < 64; ++k) { a += rp[k]; b += cp[k]; }
    w[ROWSUM_OFF / 4 + i] = a;
    w[COLSUM_OFF / 4 + i] = b;
}

__global__ __launch_bounds__(256)
void rowsum_kernel(const float* __restrict__ S, float* __restrict__ ws) {
    int row = blockIdx.x;
    const float4* p = (const float4*)(S + (size_t)row * Mm);
    float acc = 0.f;
    #pragma unroll
    for (int k = 0; k < 4; ++k) {
        float4 v = p[threadIdx.x + k * 256];
        acc += v.x + v.y + v.z + v.w;
    }
    __shared__ float red[256];
    red[threadIdx.x] = acc;
    __syncthreads();
    for (int o = 128; o > 0; o >>= 1) {
        if (threadIdx.x < o) red[threadIdx.x] += red[threadIdx.x + o];
        __syncthreads();
    }
    if (threadIdx.x == 0) ws[ROWSUM_OFF / 4 + row] = red[0];
}

__global__ __launch_bounds__(256)
void colsum_kernel(const float* __restrict__ S, float* __restrict__ ws) {
    int base = blockIdx.x * 64;
    int c = threadIdx.x & 63, stripe = threadIdx.x >> 6;
    float acc = 0.f;
    for (int r = stripe; r < Nn; r += 4) acc += S[(size_t)r * Mm + base + c];
    __shared__ float red[256];
    red[threadIdx.x] = acc;
    __syncthreads();
    if (threadIdx.x < 64) {
        float t = red[c] + red[c + 64] + red[c + 128] + red[c + 192];
        ws[COLSUM_OFF / 4 + base + c] = t;
    }
}

__global__ __launch_bounds__(256)
void histf_kernel(const float* __restrict__ S, float* __restrict__ ws) {
    __shared__ unsigned lh[NBINS];
    for (int b = threadIdx.x; b < NBINS; b += 256) lh[b] = 0;
    __syncthreads();
    const float* rowsum = ws + ROWSUM_OFF / 4;
    const float* colsum = ws + COLSUM_OFF / 4;
    unsigned* hist = (unsigned*)ws + HIST_OFF / 4;
    const float4* S4 = (const float4*)S;
    int gtid = blockIdx.x * 256 + threadIdx.x;
    const int total4 = Nn * Mm / 4;
    for (int idx = gtid; idx < total4; idx += gridDim.x * 256) {
        float4 v = S4[idx];
        int lin = idx * 4;
        int i = lin >> 12, j = lin & 4095;
        float ri = 1.0f / rowsum[i];
        float4 cv = *(const float4*)&colsum[j];
        float f0 = (v.x * ri) * (v.x / cv.x);
        float f1 = (v.y * ri) * (v.y / cv.y);
        float f2 = (v.z * ri) * (v.z / cv.z);
        float f3 = (v.w * ri) * (v.w / cv.w);
        atomicAdd(&lh[__float_as_uint(f0) >> 20], 1u);
        atomicAdd(&lh[__float_as_uint(f1) >> 20], 1u);
        atomicAdd(&lh[__float_as_uint(f2) >> 20], 1u);
        atomicAdd(&lh[__float_as_uint(f3) >> 20], 1u);
    }
    __syncthreads();
    for (int b = threadIdx.x; b < NBINS; b += 256) {
        unsigned c = lh[b];
        if (c) atomicAdd(&hist[b], c);
    }
}

__global__ __launch_bounds__(256)
void compact_scan_exact_kernel(const float* __restrict__ S, float* __restrict__ ws) {
    __shared__ unsigned lh[NBINS];
    __shared__ unsigned tauS;
    unsigned* ghist = (unsigned*)ws + HIST_OFF / 4;
    int t = threadIdx.x;
    for (int i = t; i < NBINS; i += 256) lh[i] = ghist[NBINS - 1 - i];
    __syncthreads();
    for (int st = 1; st < NBINS; st <<= 1) {
        unsigned tv[16];
        #pragma unroll
        for (int q = 0; q < 16; ++q) {
            int i = q * 256 + t;
            tv[q] = lh[i] + (i >= st ? lh[i - st] : 0u);
        }
        __syncthreads();
        #pragma unroll
        for (int q = 0; q < 16; ++q) lh[q * 256 + t] = tv[q];
        __syncthreads();
    }
    for (int i = t; i < NBINS; i += 256) {
        if (lh[i] >= KOUT && (i == 0 || lh[i - 1] < KOUT))
            tauS = (unsigned)(NBINS - 1 - i) << 20;
    }
    __syncthreads();
    const unsigned tau = tauS;

    const float* rowsum = ws + ROWSUM_OFF / 4;
    const float* colsum = ws + COLSUM_OFF / 4;
    int* counter = (int*)ws + CNT_OFF / 4;
    float* candv = ws + CANDV_OFF / 4;
    int* candi = (int*)ws + CANDI_OFF / 4;
    const float4* S4 = (const float4*)S;
    int gtid = blockIdx.x * 256 + threadIdx.x;
    const int total4 = Nn * Mm / 4;
    for (int idx = gtid; idx < total4; idx += gridDim.x * 256) {
        float4 v = S4[idx];
        int lin = idx * 4;
        int i = lin >> 12, j = lin & 4095;
        float ri = 1.0f / rowsum[i];
        float4 cv = *(const float4*)&colsum[j];
        float f[4] = {(v.x * ri) * (v.x / cv.x), (v.y * ri) * (v.y / cv.y),
                      (v.z * ri) * (v.z / cv.z), (v.w * ri) * (v.w / cv.w)};
        #pragma unroll
        for (int q = 0; q < 4; ++q) {
            if (__float_as_uint(f[q]) >= tau) {
                int p = atomicAdd(counter, 1);
                if (p < CAP) {
                    candv[p] = f[q];
                    candi[p] = lin + q;
                }
            }
        }
    }
}

__global__ __launch_bounds__(1024)
void scan_kernel(float* __restrict__ ws) {
    unsigned* hist = (unsigned*)ws + HIST_OFF / 4;
    unsigned* scano = (unsigned*)ws + SCAN_OFF / 4;
    __shared__ unsigned A[NBINS], B[NBINS];
    int t = threadIdx.x;
    for (int i = t; i < NBINS; i += 1024) A[i] = hist[NBINS - 1 - i];
    __syncthreads();
    unsigned* src = A;
    unsigned* dst = B;
    for (int st = 1; st < NBINS; st <<= 1) {
        for (int i = t; i < NBINS; i += 1024)
            dst[i] = src[i] + (i >= st ? src[i - st] : 0u);
        __syncthreads();
        unsigned* tmp = src; src = dst; dst = tmp;
    }
    for (int i = t; i < NBINS; i += 1024) {
        if (src[i] >= KOUT && (i == 0 || src[i - 1] < KOUT)) {
            scano[0] = (unsigned)(NBINS - 1 - i) << 20;
            scano[1] = src[i];
        }
    }
}

extern "C" void kernel_launch(void* const* d_in, const int* in_sizes, int n_in,
                              void* d_out, int out_size, void* d_ws, size_t ws_size,
                              hipStream_t stream) {
    const float* rf = (const float*)d_in[0];
    const float* sf = (const float*)d_in[1];
    const float* re = (const float*)d_in[2];
    const float* se = (const float*)d_in[3];
    float* ws = (float*)d_ws;
    float* out = (float*)d_out;

    if (ws_size >= NEW_REQ) {
        unsigned short* AH = (unsigned short*)((char*)d_ws + AH_OFF);
        unsigned short* AL = (unsigned short*)((char*)d_ws + AL_OFF);
        unsigned short* BH = (unsigned short*)((char*)d_ws + BH_OFF);
        unsigned short* BL = (unsigned short*)((char*)d_ws + BL_OFF);
        unsigned short* S = (unsigned short*)((char*)d_ws + SNEW_OFF);
        prep_kernel<<<640, 256, 0, stream>>>(rf, sf, re, se, AH, AL, BH, BL, ws);
        mfma_gemm_kernel<<<dim3(32, 32), 256, 0, stream>>>(
            (const __bf16*)AH, (const __bf16*)AL, (const __bf16*)BH, (const __bf16*)BL, ws, S);
        partred32_kernel<<<32, 256, 0, stream>>>(ws);
        histb_kernel<<<1024, 256, 0, stream>>>(S, ws);
        compactb_kernel<<<1024, 256, 0, stream>>>(S, ws);
        rescore_select_kernel<<<1, 1024, 0, stream>>>(rf, sf, re, se, ws, out);
    } else if (ws_size >= FAST_REQ) {
        float* S = ws + S_OFF / 4;
        dim3 tgrid(Mm / 64, Nn / 64);
        setup_kernel<<<Nn + Mm, 64, 0, stream>>>(re, se, ws);
        tile_kernel<0><<<tgrid, 256, 0, stream>>>(rf, sf, re, se, ws);
        rowsum_kernel<<<Nn, 256, 0, stream>>>(S, ws);
        colsum_kernel<<<Mm / 64, 256, 0, stream>>>(S, ws);
        histf_kernel<<<1024, 256, 0, stream>>>(S, ws);
        compact_scan_exact_kernel<<<1024, 256, 0, stream>>>(S, ws);
        select_kernel<<<1, 1024, 0, stream>>>(ws, out);
    } else {
        dim3 tgrid(Mm / 64, Nn / 64);
        setup_kernel<<<Nn + Mm, 64, 0, stream>>>(re, se, ws);
        tile_kernel<1><<<tgrid, 256, 0, stream>>>(rf, sf, re, se, ws);
        partred_kernel<<<16, 256, 0, stream>>>(ws);
        tile_kernel<2><<<tgrid, 256, 0, stream>>>(rf, sf, re, se, ws);
        scan_kernel<<<1, 1024, 0, stream>>>(ws);
        tile_kernel<3><<<tgrid, 256, 0, stream>>>(rf, sf, re, se, ws);
        select_kernel<<<1, 1024, 0, stream>>>(ws, out);
    }
}

// Round 16
// 153.167 us; speedup vs baseline: 1.2367x; 1.2367x over previous
//
#include <hip/hip_runtime.h>

#define Nn 4096
#define Mm 4096
#define Dd 512
#define Ee 128
#define KOUT 256
#define NBINS 4096
#define CAP 4096

// ---- workspace layout (bytes) ----
#define ROWSUM_OFF 0
#define COLSUM_OFF 16384
#define REN2_OFF   32768
#define SEN2_OFF   49152
#define HIST_OFF   65536
#define SCAN_OFF   81920            // fallback path only
#define CNT_OFF    81928            // [0]=cand count
#define CANDV_OFF  98304
#define CANDI_OFF  114688
// partials [4096][32] f32
#define RP32_OFF   131072
#define CP32_OFF   655360
// reciprocal sums (main path)
#define RINV_OFF   1179648
#define CINV_OFF   1196032          // ends 1212416
// old fallback partials [4096][64]
#define ROWPART_OFF 131072
#define COLPART_OFF (131072 + 1048576)
// bf16 split arrays, staging-tiled layout: each 4096*640*2 = 5 MB
#define AH_OFF   4194304
#define AL_OFF   (AH_OFF + 5242880)
#define BH_OFF   (AL_OFF + 5242880)
#define BL_OFF   (BH_OFF + 5242880)
#define SNEW_OFF 25165824            // bf16 S: 32 MB -> ends 56 MB
#define NEW_REQ  ((size_t)SNEW_OFF + (size_t)Nn * Mm * 2)
// old fallback S at 4 MB (f32)
#define S_OFF      4194304
#define FAST_REQ   ((size_t)S_OFF + (size_t)Nn * Mm * 4)

typedef float f32x4 __attribute__((ext_vector_type(4)));
typedef __bf16 bf16x8 __attribute__((ext_vector_type(8)));

// fused zero + norms (fallback paths only)
__global__ __launch_bounds__(64)
void setup_kernel(const float* __restrict__ re, const float* __restrict__ se,
                  float* __restrict__ ws) {
    int row = blockIdx.x;
    int t = threadIdx.x;
    int g4 = row * 64 + t;
    if (g4 < NBINS + 8) ((unsigned*)ws)[HIST_OFF / 4 + g4] = 0;
    const float* p = (row < Nn) ? (re + (size_t)row * Ee) : (se + (size_t)(row - Nn) * Ee);
    float x0 = p[t], x1 = p[t + 64];
    float v = x0 * x0 + x1 * x1;
    #pragma unroll
    for (int o = 32; o > 0; o >>= 1) v += __shfl_down(v, o);
    if (t == 0) {
        if (row < Nn) ws[REN2_OFF / 4 + row] = v;
        else          ws[SEN2_OFF / 4 + row - Nn] = v;
    }
}

// ---------------- MFMA path ----------------

__device__ __forceinline__ unsigned short b16rtn(float x) {
    unsigned u = __float_as_uint(x);
    return (unsigned short)((u + 0x7fffu + ((u >> 16) & 1u)) >> 16);
}
__device__ __forceinline__ void split1(float x, unsigned short& h, unsigned short& l) {
    h = b16rtn(x);
    float hf = __uint_as_float((unsigned)h << 16);
    l = b16rtn(x - hf);
}

// prep v2: tile-transposed, fully coalesced (proven R10). Zeroes hist/counter,
// computes equ norms.
__global__ __launch_bounds__(256)
void prep_kernel(const float* __restrict__ rf, const float* __restrict__ sf,
                 const float* __restrict__ re, const float* __restrict__ se,
                 unsigned short* __restrict__ AH, unsigned short* __restrict__ AL,
                 unsigned short* __restrict__ BH, unsigned short* __restrict__ BL,
                 float* __restrict__ ws) {
    __shared__ unsigned short ldsT[4][4][128][8];   // 32 KB
    const int tid = threadIdx.x;
    const int gt = blockIdx.x * 256 + tid;
    if (gt < NBINS + 8) ((unsigned*)ws)[HIST_OFF / 4 + gt] = 0;

    const int p = blockIdx.x / 20;
    const int t = blockIdx.x % 20;
    const int rowbase = p * 128;
    const bool equ = (t >= 16);
    const float* srcA = equ ? re : rf;
    const float* srcB = equ ? se : sf;
    const int stride = equ ? Ee : Dd;
    const int kcol = equ ? (t * 32 - Dd) : (t * 32);
    const float bscale = equ ? 0.1f : 1.0f;

    const int rl = tid >> 1;
    const int half = tid & 1;
    const float4* ra = (const float4*)(srcA + (size_t)(rowbase + rl) * stride + kcol + half * 16);
    const float4* rb = (const float4*)(srcB + (size_t)(rowbase + rl) * stride + kcol + half * 16);
    #pragma unroll
    for (int v4 = 0; v4 < 4; ++v4) {
        float4 a = ra[v4];
        float4 b = rb[v4];
        float av[4] = {a.x, a.y, a.z, a.w};
        float bv[4] = {b.x, b.y, b.z, b.w};
        #pragma unroll
        for (int q = 0; q < 4; ++q) {
            int kl = half * 16 + v4 * 4 + q;
            int g = kl >> 3, e = kl & 7;
            unsigned short h, l;
            split1(av[q], h, l);
            ldsT[0][g][rl][e] = h;
            ldsT[1][g][rl][e] = l;
            split1(bscale * bv[q], h, l);
            ldsT[2][g][rl][e] = h;
            ldsT[3][g][rl][e] = l;
        }
    }
    __syncthreads();
    const size_t tile = ((size_t)p * 20 + t) * 4096;
    {
        const uint4* s0 = (const uint4*)&ldsT[0][0][0][0];
        const uint4* s1 = (const uint4*)&ldsT[1][0][0][0];
        const uint4* s2 = (const uint4*)&ldsT[2][0][0][0];
        const uint4* s3 = (const uint4*)&ldsT[3][0][0][0];
        uint4* d0 = (uint4*)(AH + tile);
        uint4* d1 = (uint4*)(AL + tile);
        uint4* d2 = (uint4*)(BH + tile);
        uint4* d3 = (uint4*)(BL + tile);
        d0[tid * 2] = s0[tid * 2]; d0[tid * 2 + 1] = s0[tid * 2 + 1];
        d1[tid * 2] = s1[tid * 2]; d1[tid * 2 + 1] = s1[tid * 2 + 1];
        d2[tid * 2] = s2[tid * 2]; d2[tid * 2 + 1] = s2[tid * 2 + 1];
        d3[tid * 2] = s3[tid * 2]; d3[tid * 2 + 1] = s3[tid * 2 + 1];
    }

    if (blockIdx.x < 512) {
        int w = (tid >> 6);
        int lane = tid & 63;
        #pragma unroll
        for (int i = 0; i < 4; ++i) {
            int row = blockIdx.x * 16 + w * 4 + i;
            const float* pr = (row < Nn) ? (re + (size_t)row * Ee)
                                         : (se + (size_t)(row - Nn) * Ee);
            float x0 = pr[lane], x1 = pr[lane + 64];
            float v = x0 * x0 + x1 * x1;
            #pragma unroll
            for (int o = 32; o > 0; o >>= 1) v += __shfl_down(v, o);
            if (lane == 0) {
                if (row < Nn) ws[REN2_OFF / 4 + row] = v;
                else          ws[SEN2_OFF / 4 + row - Nn] = v;
            }
        }
    }
}

__device__ __forceinline__ void gload16(const void* g, void* l) {
    __builtin_amdgcn_global_load_lds((const __attribute__((address_space(1))) unsigned*)g,
                                     (__attribute__((address_space(3))) unsigned*)l, 16, 0, 0);
}

// Logical K = 1920: kt in [0,20) -> AH.BH, [20,40) -> AL.BH, [40,60) -> AH.BL.
// Exact f32 row/col partial sums from registers; S stored as bf16 (score map only).
__global__ __launch_bounds__(256, 4)
void mfma_gemm_kernel(const __bf16* __restrict__ AH, const __bf16* __restrict__ AL,
                      const __bf16* __restrict__ BH, const __bf16* __restrict__ BL,
                      float* __restrict__ ws, unsigned short* __restrict__ S) {
    __shared__ __bf16 lds[2][2][4096];   // 32 KB
    const int tid = threadIdx.x;
    const int lane = tid & 63, wid = tid >> 6;
    const int bx = blockIdx.x, by = blockIdx.y;
    const int rowbase = by * 128, colbase = bx * 128;
    const int wr = wid >> 1, wc = wid & 1;

    f32x4 acc[4][4];
    #pragma unroll
    for (int i = 0; i < 4; ++i)
        #pragma unroll
        for (int j = 0; j < 4; ++j) acc[i][j] = (f32x4){0.f, 0.f, 0.f, 0.f};

    auto stage = [&](int buf, int kt) {
        const int seg = (kt >= 40) ? 2 : (kt >= 20) ? 1 : 0;
        const int t = kt - seg * 20;
        const __bf16* asrc = (seg == 1) ? AL : AH;
        const __bf16* bsrc = (seg == 2) ? BL : BH;
        const __bf16* pa = asrc + ((size_t)by * 20 + t) * 4096;
        const __bf16* pb = bsrc + ((size_t)bx * 20 + t) * 4096;
        #pragma unroll
        for (int q = 0; q < 4; ++q) {
            int flat = wid * 4 + q;
            int arr = flat >> 3;
            int chunk = flat & 7;
            const __bf16* s = (arr ? pb : pa) + chunk * 512 + lane * 8;
            gload16(s, (void*)&lds[buf][arr][chunk * 512]);
        }
    };

    stage(0, 0);
    const int g = lane >> 4, c = lane & 15;
    for (int kt = 0; kt < 60; ++kt) {
        const int buf = kt & 1;
        __syncthreads();
        if (kt + 1 < 60) stage(buf ^ 1, kt + 1);
        const __bf16* Asl = &lds[buf][0][0];
        const __bf16* Bsl = &lds[buf][1][0];
        bf16x8 a[4], b[4];
        #pragma unroll
        for (int mi = 0; mi < 4; ++mi)
            a[mi] = *(const bf16x8*)&Asl[(g * 128 + wr * 64 + mi * 16 + c) * 8];
        #pragma unroll
        for (int ni = 0; ni < 4; ++ni)
            b[ni] = *(const bf16x8*)&Bsl[(g * 128 + wc * 64 + ni * 16 + c) * 8];
        #pragma unroll
        for (int mi = 0; mi < 4; ++mi)
            #pragma unroll
            for (int ni = 0; ni < 4; ++ni)
                acc[mi][ni] = __builtin_amdgcn_mfma_f32_16x16x32_bf16(a[mi], b[ni], acc[mi][ni], 0, 0, 0);
    }
    __syncthreads();

    float ren2v[4][4], sen2v[4];
    #pragma unroll
    for (int mi = 0; mi < 4; ++mi)
        #pragma unroll
        for (int q = 0; q < 4; ++q)
            ren2v[mi][q] = ws[REN2_OFF / 4 + rowbase + wr * 64 + mi * 16 + g * 4 + q];
    #pragma unroll
    for (int ni = 0; ni < 4; ++ni)
        sen2v[ni] = ws[SEN2_OFF / 4 + colbase + wc * 64 + ni * 16 + c];

    float* red = (float*)&lds[0][0][0];

    float colacc[4] = {0.f, 0.f, 0.f, 0.f};
    #pragma unroll
    for (int mi = 0; mi < 4; ++mi) {
        float rowacc[4] = {0.f, 0.f, 0.f, 0.f};
        #pragma unroll
        for (int ni = 0; ni < 4; ++ni) {
            #pragma unroll
            for (int q = 0; q < 4; ++q) {
                float e = acc[mi][ni][q] - 0.05f * (ren2v[mi][q] + sen2v[ni]) - 1.0f;
                float s = expf(e);
                acc[mi][ni][q] = s;
                rowacc[q] += s;
                colacc[ni] += s;
            }
        }
        #pragma unroll
        for (int q = 0; q < 4; ++q) {
            float v = rowacc[q];
            v += __shfl_xor(v, 1); v += __shfl_xor(v, 2);
            v += __shfl_xor(v, 4); v += __shfl_xor(v, 8);
            if (c == 0) red[wc * 128 + wr * 64 + mi * 16 + g * 4 + q] = v;
        }
    }
    #pragma unroll
    for (int ni = 0; ni < 4; ++ni) {
        float v = colacc[ni];
        v += __shfl_xor(v, 16); v += __shfl_xor(v, 32);
        if (g == 0) red[256 + wr * 128 + wc * 64 + ni * 16 + c] = v;
    }

    // S stored as bf16 (deterministic RTN)
    #pragma unroll
    for (int mi = 0; mi < 4; ++mi)
        #pragma unroll
        for (int q = 0; q < 4; ++q) {
            int r = rowbase + wr * 64 + mi * 16 + g * 4 + q;
            #pragma unroll
            for (int ni = 0; ni < 4; ++ni) {
                int cc = colbase + wc * 64 + ni * 16 + c;
                S[(size_t)r * Mm + cc] = b16rtn(acc[mi][ni][q]);
            }
        }

    __syncthreads();
    if (tid < 128) {
        ws[RP32_OFF / 4 + (size_t)(rowbase + tid) * 32 + bx] = red[tid] + red[128 + tid];
    } else {
        int t2 = tid - 128;
        ws[CP32_OFF / 4 + (size_t)(colbase + t2) * 32 + by] = red[256 + t2] + red[384 + t2];
    }
}

__global__ __launch_bounds__(256)
void partred32_kernel(float* __restrict__ w) {
    int i = blockIdx.x * 256 + threadIdx.x;   // [0, 8192)
    const float* p = (i < Nn) ? (w + RP32_OFF / 4 + (size_t)i * 32)
                              : (w + CP32_OFF / 4 + (size_t)(i - Nn) * 32);
    float a = 0.f;
    #pragma unroll
    for (int k = 0; k < 32; ++k) a += p[k];
    if (i < Nn) { w[ROWSUM_OFF / 4 + i] = a; w[RINV_OFF / 4 + i] = 1.0f / a; }
    else        { w[COLSUM_OFF / 4 + i - Nn] = a; w[CINV_OFF / 4 + i - Nn] = 1.0f / a; }
}

// ---------------- selection pipeline (bf16 map + margin + exact rescore) ----------------

__global__ __launch_bounds__(256)
void histb_kernel(const unsigned short* __restrict__ S, float* __restrict__ ws) {
    __shared__ unsigned lh[NBINS];
    for (int b = threadIdx.x; b < NBINS; b += 256) lh[b] = 0;
    __syncthreads();
    const float* rinv = ws + RINV_OFF / 4;
    const float* cinv = ws + CINV_OFF / 4;
    unsigned* hist = (unsigned*)ws + HIST_OFF / 4;
    const uint4* S8 = (const uint4*)S;
    int gtid = blockIdx.x * 256 + threadIdx.x;
    const int total8 = Nn * Mm / 8;
    for (int idx = gtid; idx < total8; idx += gridDim.x * 256) {
        uint4 v = S8[idx];
        int lin = idx * 8;
        int i = lin >> 12, j = lin & 4095;
        float ri = rinv[i];
        float4 c0 = *(const float4*)&cinv[j];
        float4 c1 = *(const float4*)&cinv[j + 4];
        unsigned uu[4] = {v.x, v.y, v.z, v.w};
        float cs[8] = {c0.x, c0.y, c0.z, c0.w, c1.x, c1.y, c1.z, c1.w};
        #pragma unroll
        for (int q = 0; q < 4; ++q) {
            float s0 = __uint_as_float((uu[q] & 0xffffu) << 16);
            float s1 = __uint_as_float((uu[q] >> 16) << 16);
            float f0 = (s0 * ri) * (s0 * cs[q * 2]);
            float f1 = (s1 * ri) * (s1 * cs[q * 2 + 1]);
            atomicAdd(&lh[__float_as_uint(f0) >> 20], 1u);
            atomicAdd(&lh[__float_as_uint(f1) >> 20], 1u);
        }
    }
    __syncthreads();
    for (int b = threadIdx.x; b < NBINS; b += 256) {
        unsigned c = lh[b];
        if (c) atomicAdd(&hist[b], c);
    }
}

// compact with replicated scan head; tau lowered by 1.5e-2 relative margin.
__global__ __launch_bounds__(256)
void compactb_kernel(const unsigned short* __restrict__ S, float* __restrict__ ws) {
    __shared__ unsigned lh[NBINS];
    __shared__ unsigned tauS;
    unsigned* ghist = (unsigned*)ws + HIST_OFF / 4;
    int t = threadIdx.x;
    for (int i = t; i < NBINS; i += 256) lh[i] = ghist[NBINS - 1 - i];
    __syncthreads();
    for (int st = 1; st < NBINS; st <<= 1) {
        unsigned tv[16];
        #pragma unroll
        for (int q = 0; q < 16; ++q) {
            int i = q * 256 + t;
            tv[q] = lh[i] + (i >= st ? lh[i - st] : 0u);
        }
        __syncthreads();
        #pragma unroll
        for (int q = 0; q < 16; ++q) lh[q * 256 + t] = tv[q];
        __syncthreads();
    }
    for (int i = t; i < NBINS; i += 256) {
        if (lh[i] >= KOUT && (i == 0 || lh[i - 1] < KOUT))
            tauS = (unsigned)(NBINS - 1 - i) << 20;
    }
    __syncthreads();
    const float tauf = __uint_as_float(tauS) * (1.0f - 1.5e-2f);

    const float* rinv = ws + RINV_OFF / 4;
    const float* cinv = ws + CINV_OFF / 4;
    int* counter = (int*)ws + CNT_OFF / 4;
    float* candv = ws + CANDV_OFF / 4;
    int* candi = (int*)ws + CANDI_OFF / 4;
    const uint4* S8 = (const uint4*)S;
    int gtid = blockIdx.x * 256 + threadIdx.x;
    const int total8 = Nn * Mm / 8;
    for (int idx = gtid; idx < total8; idx += gridDim.x * 256) {
        uint4 v = S8[idx];
        int lin = idx * 8;
        int i = lin >> 12, j = lin & 4095;
        float ri = rinv[i];
        float4 c0 = *(const float4*)&cinv[j];
        float4 c1 = *(const float4*)&cinv[j + 4];
        unsigned uu[4] = {v.x, v.y, v.z, v.w};
        float cs[8] = {c0.x, c0.y, c0.z, c0.w, c1.x, c1.y, c1.z, c1.w};
        #pragma unroll
        for (int q = 0; q < 8; ++q) {
            unsigned hw = (q & 1) ? (uu[q >> 1] >> 16) : (uu[q >> 1] & 0xffffu);
            float s = __uint_as_float(hw << 16);
            float f = (s * ri) * (s * cs[q]);
            if (f >= tauf) {
                int p = atomicAdd(counter, 1);
                if (p < CAP) {
                    candv[p] = f;
                    candi[p] = lin + q;
                }
            }
        }
    }
}

// exact f32 rescore from ORIGINAL inputs + exact sums (one wave per candidate).
__global__ __launch_bounds__(256)
void rescore_kernel(const float* __restrict__ rf, const float* __restrict__ sf,
                    const float* __restrict__ re, const float* __restrict__ se,
                    float* __restrict__ ws) {
    const int* counter = (const int*)ws + CNT_OFF / 4;
    int n = *counter;
    if (n > CAP) n = CAP;
    const int cid = blockIdx.x * 4 + (threadIdx.x >> 6);
    if (cid >= n) return;
    const int lane = threadIdx.x & 63;
    const int idx = ((const int*)ws + CANDI_OFF / 4)[cid];
    const int r = idx >> 12, c = idx & (Mm - 1);
    float d1 = 0.f, d2 = 0.f;
    const float* ar = rf + (size_t)r * Dd;
    const float* bc = sf + (size_t)c * Dd;
    #pragma unroll
    for (int k = 0; k < 8; ++k) d1 = fmaf(ar[lane + k * 64], bc[lane + k * 64], d1);
    const float* er = re + (size_t)r * Ee;
    const float* ec = se + (size_t)c * Ee;
    #pragma unroll
    for (int k = 0; k < 2; ++k) d2 = fmaf(er[lane + k * 64], ec[lane + k * 64], d2);
    #pragma unroll
    for (int o = 32; o > 0; o >>= 1) {
        d1 += __shfl_xor(d1, o);
        d2 += __shfl_xor(d2, o);
    }
    if (lane == 0) {
        float rn = ws[REN2_OFF / 4 + r], cn = ws[SEN2_OFF / 4 + c];
        float e1 = fmaxf(2.0f - 2.0f * d1, 0.0f);
        float e2 = fmaxf(rn + cn - 2.0f * d2, 0.0f);
        float s = expf(-(0.5f * e1 + 0.05f * e2));
        float R = ws[ROWSUM_OFF / 4 + r], C = ws[COLSUM_OFF / 4 + c];
        (ws + CANDV_OFF / 4)[cid] = (s / R) * (s / C);
    }
}

__global__ __launch_bounds__(1024)
void select_kernel(const float* __restrict__ ws, float* __restrict__ out) {
    const int* counter = (const int*)ws + CNT_OFF / 4;
    const float* candv = ws + CANDV_OFF / 4;
    const int* candi = (const int*)ws + CANDI_OFF / 4;
    int n = *counter;
    if (n > CAP) n = CAP;
    int P = 256;
    while (P < n) P <<= 1;
    __shared__ float v[CAP];
    __shared__ int id[CAP];
    int t = threadIdx.x;
    for (int i = t; i < P; i += 1024) {
        if (i < n) { v[i] = candv[i]; id[i] = candi[i]; }
        else       { v[i] = -1.0f;    id[i] = 0x7fffffff; }
    }
    __syncthreads();
    for (int k = 2; k <= P; k <<= 1) {
        for (int j = k >> 1; j > 0; j >>= 1) {
            for (int i = t; i < P; i += 1024) {
                int ixj = i ^ j;
                if (ixj > i) {
                    float va = v[i], vb = v[ixj];
                    int ia = id[i], ib = id[ixj];
                    bool aFirst = (va > vb) || (va == vb && ia < ib);
                    bool up = ((i & k) == 0);
                    if (up ? !aFirst : aFirst) {
                        v[i] = vb; v[ixj] = va;
                        id[i] = ib; id[ixj] = ia;
                    }
                }
            }
            __syncthreads();
        }
    }
    if (t < KOUT) {
        int idx = id[t];
        out[t]            = (float)(idx >> 12);
        out[KOUT + t]     = (float)(idx & (Mm - 1));
        out[2 * KOUT + t] = v[t];
    }
}

// ---------------- old f32 fallback path (proven R2) ----------------

template <int MODE>
__global__ __launch_bounds__(256)
void tile_kernel(const float* __restrict__ rf, const float* __restrict__ sf,
                 const float* __restrict__ re, const float* __restrict__ se,
                 float* __restrict__ ws) {
    const int bx = blockIdx.x, by = blockIdx.y;
    const int tid = threadIdx.x;
    const int tx = tid & 15, ty = tid >> 4;
    const int rowbase = by * 64, colbase = bx * 64;

    __shared__ float As[16][68];
    __shared__ float Bs[16][68];

    float acc1[4][4] = {};
    float acc2[4][4] = {};

    for (int kk = 0; kk < Dd; kk += 16) {
        #pragma unroll
        for (int i = 0; i < 4; ++i) {
            int f = tid + i * 256;
            int r = f >> 4, c = f & 15;
            As[c][r] = rf[(size_t)(rowbase + r) * Dd + kk + c];
            Bs[c][r] = sf[(size_t)(colbase + r) * Dd + kk + c];
        }
        __syncthreads();
        #pragma unroll
        for (int k = 0; k < 16; ++k) {
            float a[4], b[4];
            #pragma unroll
            for (int i = 0; i < 4; ++i) a[i] = As[k][ty * 4 + i];
            #pragma unroll
            for (int j = 0; j < 4; ++j) b[j] = Bs[k][tx * 4 + j];
            #pragma unroll
            for (int i = 0; i < 4; ++i)
                #pragma unroll
                for (int j = 0; j < 4; ++j)
                    acc1[i][j] = fmaf(a[i], b[j], acc1[i][j]);
        }
        __syncthreads();
    }
    for (int kk = 0; kk < Ee; kk += 16) {
        #pragma unroll
        for (int i = 0; i < 4; ++i) {
            int f = tid + i * 256;
            int r = f >> 4, c = f & 15;
            As[c][r] = re[(size_t)(rowbase + r) * Ee + kk + c];
            Bs[c][r] = se[(size_t)(colbase + r) * Ee + kk + c];
        }
        __syncthreads();
        #pragma unroll
        for (int k = 0; k < 16; ++k) {
            float a[4], b[4];
            #pragma unroll
            for (int i = 0; i < 4; ++i) a[i] = As[k][ty * 4 + i];
            #pragma unroll
            for (int j = 0; j < 4; ++j) b[j] = Bs[k][tx * 4 + j];
            #pragma unroll
            for (int i = 0; i < 4; ++i)
                #pragma unroll
                for (int j = 0; j < 4; ++j)
                    acc2[i][j] = fmaf(a[i], b[j], acc2[i][j]);
        }
        __syncthreads();
    }

    const int r0 = rowbase + ty * 4, c0 = colbase + tx * 4;
    float rn[4], cn[4];
    #pragma unroll
    for (int i = 0; i < 4; ++i) rn[i] = ws[REN2_OFF / 4 + r0 + i];
    #pragma unroll
    for (int j = 0; j < 4; ++j) cn[j] = ws[SEN2_OFF / 4 + c0 + j];

    float s[4][4];
    #pragma unroll
    for (int i = 0; i < 4; ++i)
        #pragma unroll
        for (int j = 0; j < 4; ++j) {
            float d1 = fmaxf(2.0f - 2.0f * acc1[i][j], 0.0f);
            float sq = fmaxf(rn[i] + cn[j] - 2.0f * acc2[i][j], 0.0f);
            s[i][j] = expf(-(0.5f * d1 + 0.05f * sq));
        }

    if constexpr (MODE == 0) {
        float* S = ws + S_OFF / 4;
        #pragma unroll
        for (int i = 0; i < 4; ++i) {
            float4 v = make_float4(s[i][0], s[i][1], s[i][2], s[i][3]);
            *(float4*)&S[(size_t)(r0 + i) * Mm + c0] = v;
        }
    }
    if constexpr (MODE == 1) {
        __shared__ float red[64][17];
        #pragma unroll
        for (int i = 0; i < 4; ++i)
            red[ty * 4 + i][tx] = s[i][0] + s[i][1] + s[i][2] + s[i][3];
        __syncthreads();
        if (tid < 64) {
            float t = 0.f;
            #pragma unroll
            for (int k = 0; k < 16; ++k) t += red[tid][k];
            ws[ROWPART_OFF / 4 + (size_t)(rowbase + tid) * 64 + bx] = t;
        }
        __syncthreads();
        #pragma unroll
        for (int j = 0; j < 4; ++j)
            red[tx * 4 + j][ty] = s[0][j] + s[1][j] + s[2][j] + s[3][j];
        __syncthreads();
        if (tid < 64) {
            float t = 0.f;
            #pragma unroll
            for (int k = 0; k < 16; ++k) t += red[tid][k];
            ws[COLPART_OFF / 4 + (size_t)(colbase + tid) * 64 + by] = t;
        }
    }
    if constexpr (MODE == 2) {
        __shared__ unsigned lh[NBINS];
        for (int b = tid; b < NBINS; b += 256) lh[b] = 0;
        __syncthreads();
        float rs[4], cs[4];
        #pragma unroll
        for (int i = 0; i < 4; ++i) rs[i] = ws[ROWSUM_OFF / 4 + r0 + i];
        #pragma unroll
        for (int j = 0; j < 4; ++j) cs[j] = ws[COLSUM_OFF / 4 + c0 + j];
        #pragma unroll
        for (int i = 0; i < 4; ++i)
            #pragma unroll
            for (int j = 0; j < 4; ++j) {
                float f = (s[i][j] / rs[i]) * (s[i][j] / cs[j]);
                atomicAdd(&lh[__float_as_uint(f) >> 20], 1u);
            }
        __syncthreads();
        unsigned* hist = (unsigned*)ws + HIST_OFF / 4;
        for (int b = tid; b < NBINS; b += 256) {
            unsigned cc = lh[b];
            if (cc) atomicAdd(&hist[b], cc);
        }
    }
    if constexpr (MODE == 3) {
        unsigned tau = ((unsigned*)ws)[SCAN_OFF / 4];
        int* counter = (int*)ws + CNT_OFF / 4;
        float* candv = ws + CANDV_OFF / 4;
        int* candi = (int*)ws + CANDI_OFF / 4;
        float rs[4], cs[4];
        #pragma unroll
        for (int i = 0; i < 4; ++i) rs[i] = ws[ROWSUM_OFF / 4 + r0 + i];
        #pragma unroll
        for (int j = 0; j < 4; ++j) cs[j] = ws[COLSUM_OFF / 4 + c0 + j];
        #pragma unroll
        for (int i = 0; i < 4; ++i)
            #pragma unroll
            for (int j = 0; j < 4; ++j) {
                float f = (s[i][j] / rs[i]) * (s[i][j] / cs[j]);
                if (__float_as_uint(f) >= tau) {
                    int p = atomicAdd(counter, 1);
                    if (p < CAP) {
                        candv[p] = f;
                        candi[p] = (r0 + i) * Mm + (c0 + j);
                    }
                }
            }
    }
}

__global__ __launch_bounds__(256)
void partred_kernel(float* __restrict__ w) {
    int i = blockIdx.x * 256 + threadIdx.x;
    const float* rp = w + ROWPART_OFF / 4 + (size_t)i * 64;
    const float* cp = w + COLPART_OFF / 4 + (size_t)i * 64;
    float a = 0.f, b = 0.f;
    #pragma unroll
    for (int k = 0; k < 64; ++k) { a += rp[k]; b += cp[k]; }
    w[ROWSUM_OFF / 4 + i] = a;
    w[COLSUM_OFF / 4 + i] = b;
}

__global__ __launch_bounds__(256)
void rowsum_kernel(const float* __restrict__ S, float* __restrict__ ws) {
    int row = blockIdx.x;
    const float4* p = (const float4*)(S + (size_t)row * Mm);
    float acc = 0.f;
    #pragma unroll
    for (int k = 0; k < 4; ++k) {
        float4 v = p[threadIdx.x + k * 256];
        acc += v.x + v.y + v.z + v.w;
    }
    __shared__ float red[256];
    red[threadIdx.x] = acc;
    __syncthreads();
    for (int o = 128; o > 0; o >>= 1) {
        if (threadIdx.x < o) red[threadIdx.x] += red[threadIdx.x + o];
        __syncthreads();
    }
    if (threadIdx.x == 0) ws[ROWSUM_OFF / 4 + row] = red[0];
}

__global__ __launch_bounds__(256)
void colsum_kernel(const float* __restrict__ S, float* __restrict__ ws) {
    int base = blockIdx.x * 64;
    int c = threadIdx.x & 63, stripe = threadIdx.x >> 6;
    float acc = 0.f;
    for (int r = stripe; r < Nn; r += 4) acc += S[(size_t)r * Mm + base + c];
    __shared__ float red[256];
    red[threadIdx.x] = acc;
    __syncthreads();
    if (threadIdx.x < 64) {
        float t = red[c] + red[c + 64] + red[c + 128] + red[c + 192];
        ws[COLSUM_OFF / 4 + base + c] = t;
    }
}

__global__ __launch_bounds__(256)
void histf_kernel(const float* __restrict__ S, float* __restrict__ ws) {
    __shared__ unsigned lh[NBINS];
    for (int b = threadIdx.x; b < NBINS; b += 256) lh[b] = 0;
    __syncthreads();
    const float* rowsum = ws + ROWSUM_OFF / 4;
    const float* colsum = ws + COLSUM_OFF / 4;
    unsigned* hist = (unsigned*)ws + HIST_OFF / 4;
    const float4* S4 = (const float4*)S;
    int gtid = blockIdx.x * 256 + threadIdx.x;
    const int total4 = Nn * Mm / 4;
    for (int idx = gtid; idx < total4; idx += gridDim.x * 256) {
        float4 v = S4[idx];
        int lin = idx * 4;
        int i = lin >> 12, j = lin & 4095;
        float ri = 1.0f / rowsum[i];
        float4 cv = *(const float4*)&colsum[j];
        float f0 = (v.x * ri) * (v.x / cv.x);
        float f1 = (v.y * ri) * (v.y / cv.y);
        float f2 = (v.z * ri) * (v.z / cv.z);
        float f3 = (v.w * ri) * (v.w / cv.w);
        atomicAdd(&lh[__float_as_uint(f0) >> 20], 1u);
        atomicAdd(&lh[__float_as_uint(f1) >> 20], 1u);
        atomicAdd(&lh[__float_as_uint(f2) >> 20], 1u);
        atomicAdd(&lh[__float_as_uint(f3) >> 20], 1u);
    }
    __syncthreads();
    for (int b = threadIdx.x; b < NBINS; b += 256) {
        unsigned c = lh[b];
        if (c) atomicAdd(&hist[b], c);
    }
}

__global__ __launch_bounds__(256)
void compact_scan_exact_kernel(const float* __restrict__ S, float* __restrict__ ws) {
    __shared__ unsigned lh[NBINS];
    __shared__ unsigned tauS;
    unsigned* ghist = (unsigned*)ws + HIST_OFF / 4;
    int t = threadIdx.x;
    for (int i = t; i < NBINS; i += 256) lh[i] = ghist[NBINS - 1 - i];
    __syncthreads();
    for (int st = 1; st < NBINS; st <<= 1) {
        unsigned tv[16];
        #pragma unroll
        for (int q = 0; q < 16; ++q) {
            int i = q * 256 + t;
            tv[q] = lh[i] + (i >= st ? lh[i - st] : 0u);
        }
        __syncthreads();
        #pragma unroll
        for (int q = 0; q < 16; ++q) lh[q * 256 + t] = tv[q];
        __syncthreads();
    }
    for (int i = t; i < NBINS; i += 256) {
        if (lh[i] >= KOUT && (i == 0 || lh[i - 1] < KOUT))
            tauS = (unsigned)(NBINS - 1 - i) << 20;
    }
    __syncthreads();
    const unsigned tau = tauS;

    const float* rowsum = ws + ROWSUM_OFF / 4;
    const float* colsum = ws + COLSUM_OFF / 4;
    int* counter = (int*)ws + CNT_OFF / 4;
    float* candv = ws + CANDV_OFF / 4;
    int* candi = (int*)ws + CANDI_OFF / 4;
    const float4* S4 = (const float4*)S;
    int gtid = blockIdx.x * 256 + threadIdx.x;
    const int total4 = Nn * Mm / 4;
    for (int idx = gtid; idx < total4; idx += gridDim.x * 256) {
        float4 v = S4[idx];
        int lin = idx * 4;
        int i = lin >> 12, j = lin & 4095;
        float ri = 1.0f / rowsum[i];
        float4 cv = *(const float4*)&colsum[j];
        float f[4] = {(v.x * ri) * (v.x / cv.x), (v.y * ri) * (v.y / cv.y),
                      (v.z * ri) * (v.z / cv.z), (v.w * ri) * (v.w / cv.w)};
        #pragma unroll
        for (int q = 0; q < 4; ++q) {
            if (__float_as_uint(f[q]) >= tau) {
                int p = atomicAdd(counter, 1);
                if (p < CAP) {
                    candv[p] = f[q];
                    candi[p] = lin + q;
                }
            }
        }
    }
}

__global__ __launch_bounds__(1024)
void scan_kernel(float* __restrict__ ws) {
    unsigned* hist = (unsigned*)ws + HIST_OFF / 4;
    unsigned* scano = (unsigned*)ws + SCAN_OFF / 4;
    __shared__ unsigned A[NBINS], B[NBINS];
    int t = threadIdx.x;
    for (int i = t; i < NBINS; i += 1024) A[i] = hist[NBINS - 1 - i];
    __syncthreads();
    unsigned* src = A;
    unsigned* dst = B;
    for (int st = 1; st < NBINS; st <<= 1) {
        for (int i = t; i < NBINS; i += 1024)
            dst[i] = src[i] + (i >= st ? src[i - st] : 0u);
        __syncthreads();
        unsigned* tmp = src; src = dst; dst = tmp;
    }
    for (int i = t; i < NBINS; i += 1024) {
        if (src[i] >= KOUT && (i == 0 || src[i - 1] < KOUT)) {
            scano[0] = (unsigned)(NBINS - 1 - i) << 20;
            scano[1] = src[i];
        }
    }
}

extern "C" void kernel_launch(void* const* d_in, const int* in_sizes, int n_in,
                              void* d_out, int out_size, void* d_ws, size_t ws_size,
                              hipStream_t stream) {
    const float* rf = (const float*)d_in[0];
    const float* sf = (const float*)d_in[1];
    const float* re = (const float*)d_in[2];
    const float* se = (const float*)d_in[3];
    float* ws = (float*)d_ws;
    float* out = (float*)d_out;

    if (ws_size >= NEW_REQ) {
        unsigned short* AH = (unsigned short*)((char*)d_ws + AH_OFF);
        unsigned short* AL = (unsigned short*)((char*)d_ws + AL_OFF);
        unsigned short* BH = (unsigned short*)((char*)d_ws + BH_OFF);
        unsigned short* BL = (unsigned short*)((char*)d_ws + BL_OFF);
        unsigned short* S = (unsigned short*)((char*)d_ws + SNEW_OFF);
        prep_kernel<<<640, 256, 0, stream>>>(rf, sf, re, se, AH, AL, BH, BL, ws);
        mfma_gemm_kernel<<<dim3(32, 32), 256, 0, stream>>>(
            (const __bf16*)AH, (const __bf16*)AL, (const __bf16*)BH, (const __bf16*)BL, ws, S);
        partred32_kernel<<<32, 256, 0, stream>>>(ws);
        histb_kernel<<<1024, 256, 0, stream>>>(S, ws);
        compactb_kernel<<<1024, 256, 0, stream>>>(S, ws);
        rescore_kernel<<<1024, 256, 0, stream>>>(rf, sf, re, se, ws);
        select_kernel<<<1, 1024, 0, stream>>>(ws, out);
    } else if (ws_size >= FAST_REQ) {
        float* S = ws + S_OFF / 4;
        dim3 tgrid(Mm / 64, Nn / 64);
        setup_kernel<<<Nn + Mm, 64, 0, stream>>>(re, se, ws);
        tile_kernel<0><<<tgrid, 256, 0, stream>>>(rf, sf, re, se, ws);
        rowsum_kernel<<<Nn, 256, 0, stream>>>(S, ws);
        colsum_kernel<<<Mm / 64, 256, 0, stream>>>(S, ws);
        histf_kernel<<<1024, 256, 0, stream>>>(S, ws);
        compact_scan_exact_kernel<<<1024, 256, 0, stream>>>(S, ws);
        select_kernel<<<1, 1024, 0, stream>>>(ws, out);
    } else {
        dim3 tgrid(Mm / 64, Nn / 64);
        setup_kernel<<<Nn + Mm, 64, 0, stream>>>(re, se, ws);
        tile_kernel<1><<<tgrid, 256, 0, stream>>>(rf, sf, re, se, ws);
        partred_kernel<<<16, 256, 0, stream>>>(ws);
        tile_kernel<2><<<tgrid, 256, 0, stream>>>(rf, sf, re, se, ws);
        scan_kernel<<<1, 1024, 0, stream>>>(ws);
        tile_kernel<3><<<tgrid, 256, 0, stream>>>(rf, sf, re, se, ws);
        select_kernel<<<1, 1024, 0, stream>>>(ws, out);
    }
}

// Round 17
// 144.211 us; speedup vs baseline: 1.3135x; 1.0621x over previous
//
#include <hip/hip_runtime.h>

#define Nn 4096
#define Mm 4096
#define Dd 512
#define Ee 128
#define KOUT 256
#define NBINS 4096
#define CAP 4096

// ---- workspace layout (bytes) ----
#define ROWSUM_OFF 0
#define COLSUM_OFF 16384
#define REN2_OFF   32768
#define SEN2_OFF   49152
#define HIST_OFF   65536
#define SCAN_OFF   81920            // fallback path only
#define CNT_OFF    81928            // [0]=cand count
#define CANDV_OFF  98304
#define CANDI_OFF  114688
// partials [4096][16] f32 (main path)
#define RP16_OFF   131072
#define CP16_OFF   393216           // ends 655360
// reciprocal sums (main path)
#define RINV_OFF   1179648
#define CINV_OFF   1196032          // ends 1212416
// old fallback partials [4096][64]
#define ROWPART_OFF 131072
#define COLPART_OFF (131072 + 1048576)
// bf16 split arrays, 64k-tile packed layout: each 4096*640*2 = 5 MB
#define AH_OFF   4194304
#define AL_OFF   (AH_OFF + 5242880)
#define BH_OFF   (AL_OFF + 5242880)
#define BL_OFF   (BH_OFF + 5242880)
#define SNEW_OFF 25165824            // bf16 S: 32 MB -> ends 56 MB
#define NEW_REQ  ((size_t)SNEW_OFF + (size_t)Nn * Mm * 2)
// old fallback S at 4 MB (f32)
#define S_OFF      4194304
#define FAST_REQ   ((size_t)S_OFF + (size_t)Nn * Mm * 4)

typedef float f32x4 __attribute__((ext_vector_type(4)));
typedef __bf16 bf16x8 __attribute__((ext_vector_type(8)));

// fused zero + norms (fallback paths only)
__global__ __launch_bounds__(64)
void setup_kernel(const float* __restrict__ re, const float* __restrict__ se,
                  float* __restrict__ ws) {
    int row = blockIdx.x;
    int t = threadIdx.x;
    int g4 = row * 64 + t;
    if (g4 < NBINS + 8) ((unsigned*)ws)[HIST_OFF / 4 + g4] = 0;
    const float* p = (row < Nn) ? (re + (size_t)row * Ee) : (se + (size_t)(row - Nn) * Ee);
    float x0 = p[t], x1 = p[t + 64];
    float v = x0 * x0 + x1 * x1;
    #pragma unroll
    for (int o = 32; o > 0; o >>= 1) v += __shfl_down(v, o);
    if (t == 0) {
        if (row < Nn) ws[REN2_OFF / 4 + row] = v;
        else          ws[SEN2_OFF / 4 + row - Nn] = v;
    }
}

// ---------------- MFMA path ----------------

__device__ __forceinline__ unsigned short b16rtn(float x) {
    unsigned u = __float_as_uint(x);
    return (unsigned short)((u + 0x7fffu + ((u >> 16) & 1u)) >> 16);
}
__device__ __forceinline__ void split1(float x, unsigned short& h, unsigned short& l) {
    h = b16rtn(x);
    float hf = __uint_as_float((unsigned)h << 16);
    l = b16rtn(x - hf);
}

// prep v3: packed for 256-row panels x 64-k tiles: elem offset =
// (panel256*10 + ktile64)*16384 + g8*2048 + row255*8 + e   (g8 = (k%64)/8)
// Block = (128-row, 32-k) chunk as before; zeroes hist/counter; equ norms.
__global__ __launch_bounds__(256)
void prep_kernel(const float* __restrict__ rf, const float* __restrict__ sf,
                 const float* __restrict__ re, const float* __restrict__ se,
                 unsigned short* __restrict__ AH, unsigned short* __restrict__ AL,
                 unsigned short* __restrict__ BH, unsigned short* __restrict__ BL,
                 float* __restrict__ ws) {
    __shared__ unsigned short ldsT[4][4][128][8];   // [arr][g][r][e] = 32 KB
    const int tid = threadIdx.x;
    const int gt = blockIdx.x * 256 + tid;
    if (gt < NBINS + 8) ((unsigned*)ws)[HIST_OFF / 4 + gt] = 0;

    const int p128 = blockIdx.x / 20;      // 0..31
    const int t32 = blockIdx.x % 20;       // 0..19
    const int rowbase = p128 * 128;
    const bool equ = (t32 >= 16);
    const float* srcA = equ ? re : rf;
    const float* srcB = equ ? se : sf;
    const int stride = equ ? Ee : Dd;
    const int kcol = equ ? (t32 * 32 - Dd) : (t32 * 32);
    const float bscale = equ ? 0.1f : 1.0f;

    const int rl = tid >> 1;
    const int half = tid & 1;
    const float4* ra = (const float4*)(srcA + (size_t)(rowbase + rl) * stride + kcol + half * 16);
    const float4* rb = (const float4*)(srcB + (size_t)(rowbase + rl) * stride + kcol + half * 16);
    #pragma unroll
    for (int v4 = 0; v4 < 4; ++v4) {
        float4 a = ra[v4];
        float4 b = rb[v4];
        float av[4] = {a.x, a.y, a.z, a.w};
        float bv[4] = {b.x, b.y, b.z, b.w};
        #pragma unroll
        for (int q = 0; q < 4; ++q) {
            int kl = half * 16 + v4 * 4 + q;
            int g = kl >> 3, e = kl & 7;
            unsigned short h, l;
            split1(av[q], h, l);
            ldsT[0][g][rl][e] = h;
            ldsT[1][g][rl][e] = l;
            split1(bscale * bv[q], h, l);
            ldsT[2][g][rl][e] = h;
            ldsT[3][g][rl][e] = l;
        }
    }
    __syncthreads();
    // output: panel256/khalf mapping
    const int panel256 = p128 >> 1, rhalf = p128 & 1;
    int ktile64, khalf;
    if (t32 < 16) { ktile64 = t32 >> 1; khalf = t32 & 1; }
    else          { int tt = t32 - 16; ktile64 = 8 + (tt >> 1); khalf = tt & 1; }
    const size_t base_u4 = ((size_t)(panel256 * 10 + ktile64) * 8) * 256;  // uint4 units
    {
        const uint4* s0 = (const uint4*)&ldsT[0][0][0][0];
        const uint4* s1 = (const uint4*)&ldsT[1][0][0][0];
        const uint4* s2 = (const uint4*)&ldsT[2][0][0][0];
        const uint4* s3 = (const uint4*)&ldsT[3][0][0][0];
        uint4* d0 = (uint4*)AH;
        uint4* d1 = (uint4*)AL;
        uint4* d2 = (uint4*)BH;
        uint4* d3 = (uint4*)BL;
        #pragma unroll
        for (int v = 0; v < 2; ++v) {
            int flat = tid * 2 + v;            // 0..511
            int g = flat >> 7, within = flat & 127;
            size_t du = base_u4 + (size_t)(khalf * 4 + g) * 256 + rhalf * 128 + within;
            d0[du] = s0[flat];
            d1[du] = s1[flat];
            d2[du] = s2[flat];
            d3[du] = s3[flat];
        }
    }

    if (blockIdx.x < 512) {
        int w = (tid >> 6);
        int lane = tid & 63;
        #pragma unroll
        for (int i = 0; i < 4; ++i) {
            int row = blockIdx.x * 16 + w * 4 + i;
            const float* pr = (row < Nn) ? (re + (size_t)row * Ee)
                                         : (se + (size_t)(row - Nn) * Ee);
            float x0 = pr[lane], x1 = pr[lane + 64];
            float v = x0 * x0 + x1 * x1;
            #pragma unroll
            for (int o = 32; o > 0; o >>= 1) v += __shfl_down(v, o);
            if (lane == 0) {
                if (row < Nn) ws[REN2_OFF / 4 + row] = v;
                else          ws[SEN2_OFF / 4 + row - Nn] = v;
            }
        }
    }
}

__device__ __forceinline__ void gload16(const void* g, void* l) {
    __builtin_amdgcn_global_load_lds((const __attribute__((address_space(1))) unsigned*)g,
                                     (__attribute__((address_space(3))) unsigned*)l, 16, 0, 0);
}

// 256x256 tile, BK=64, 8 waves (2x4), 128 KB LDS dbuf, 30 K-tiles
// (logical K=1920: kt<10 AH.BH, 10..20 AL.BH, 20..30 AH.BL).
// LDS layout per buffer: A[g8(8)][256][8] then B same (fragment-major, conflict-free).
__global__ __launch_bounds__(512, 1)
void mfma_gemm_kernel(const __bf16* __restrict__ AH, const __bf16* __restrict__ AL,
                      const __bf16* __restrict__ BH, const __bf16* __restrict__ BL,
                      float* __restrict__ ws, unsigned short* __restrict__ S) {
    __shared__ __bf16 lds[2][2][16384];   // [dbuf][A/B] = 128 KB
    const int tid = threadIdx.x;
    const int lane = tid & 63, wid = tid >> 6;
    const int bx = blockIdx.x, by = blockIdx.y;
    const int rowbase = by * 256, colbase = bx * 256;
    const int wr = wid >> 2, wc = wid & 3;     // 2 x 4 waves
    const int g = lane >> 4, c = lane & 15;

    f32x4 acc[8][4];
    #pragma unroll
    for (int i = 0; i < 8; ++i)
        #pragma unroll
        for (int j = 0; j < 4; ++j) acc[i][j] = (f32x4){0.f, 0.f, 0.f, 0.f};

    auto stage = [&](int buf, int kt) {
        const int seg = (kt >= 20) ? 2 : (kt >= 10) ? 1 : 0;
        const int t10 = kt - seg * 10;
        const __bf16* asrc = (seg == 1) ? AL : AH;
        const __bf16* bsrc = (seg == 2) ? BL : BH;
        const __bf16* pa = asrc + ((size_t)by * 10 + t10) * 16384;
        const __bf16* pb = bsrc + ((size_t)bx * 10 + t10) * 16384;
        #pragma unroll
        for (int i = 0; i < 8; ++i) {
            int flat = i * 512 + tid;          // 0..4095 (uint4 units)
            int arr = flat >> 11;              // 0=A, 1=B
            int off = flat & 2047;
            const __bf16* s = (arr ? pb : pa) + off * 8;
            gload16(s, (void*)&lds[buf][arr][off * 8]);
        }
    };

    stage(0, 0);
    for (int kt = 0; kt < 30; ++kt) {
        const int buf = kt & 1;
        __syncthreads();
        if (kt + 1 < 30) stage(buf ^ 1, kt + 1);
        const __bf16* Asl = &lds[buf][0][0];
        const __bf16* Bsl = &lds[buf][1][0];

        bf16x8 aL[4][2], aH[4][2], bL[2][2], bH[2][2];
        // A-low: rows wr*128 + mi*16 + c, mi 0..3; g8 = K2*4 + g
        #pragma unroll
        for (int mi = 0; mi < 4; ++mi)
            #pragma unroll
            for (int K2 = 0; K2 < 2; ++K2)
                aL[mi][K2] = *(const bf16x8*)&Asl[((K2 * 4 + g) * 2048 + (wr * 128 + mi * 16 + c) * 8)];
        #pragma unroll
        for (int ni = 0; ni < 2; ++ni)
            #pragma unroll
            for (int K2 = 0; K2 < 2; ++K2)
                bL[ni][K2] = *(const bf16x8*)&Bsl[((K2 * 4 + g) * 2048 + (wc * 64 + ni * 16 + c) * 8)];
        // Q0: aL x bL
        #pragma unroll
        for (int mi = 0; mi < 4; ++mi)
            #pragma unroll
            for (int ni = 0; ni < 2; ++ni) {
                acc[mi][ni] = __builtin_amdgcn_mfma_f32_16x16x32_bf16(aL[mi][0], bL[ni][0], acc[mi][ni], 0, 0, 0);
                acc[mi][ni] = __builtin_amdgcn_mfma_f32_16x16x32_bf16(aL[mi][1], bL[ni][1], acc[mi][ni], 0, 0, 0);
            }
        #pragma unroll
        for (int ni = 0; ni < 2; ++ni)
            #pragma unroll
            for (int K2 = 0; K2 < 2; ++K2)
                bH[ni][K2] = *(const bf16x8*)&Bsl[((K2 * 4 + g) * 2048 + (wc * 64 + (ni + 2) * 16 + c) * 8)];
        // Q1: aL x bH
        #pragma unroll
        for (int mi = 0; mi < 4; ++mi)
            #pragma unroll
            for (int ni = 0; ni < 2; ++ni) {
                acc[mi][ni + 2] = __builtin_amdgcn_mfma_f32_16x16x32_bf16(aL[mi][0], bH[ni][0], acc[mi][ni + 2], 0, 0, 0);
                acc[mi][ni + 2] = __builtin_amdgcn_mfma_f32_16x16x32_bf16(aL[mi][1], bH[ni][1], acc[mi][ni + 2], 0, 0, 0);
            }
        #pragma unroll
        for (int mi = 0; mi < 4; ++mi)
            #pragma unroll
            for (int K2 = 0; K2 < 2; ++K2)
                aH[mi][K2] = *(const bf16x8*)&Asl[((K2 * 4 + g) * 2048 + (wr * 128 + (mi + 4) * 16 + c) * 8)];
        // Q2: aH x bL
        #pragma unroll
        for (int mi = 0; mi < 4; ++mi)
            #pragma unroll
            for (int ni = 0; ni < 2; ++ni) {
                acc[mi + 4][ni] = __builtin_amdgcn_mfma_f32_16x16x32_bf16(aH[mi][0], bL[ni][0], acc[mi + 4][ni], 0, 0, 0);
                acc[mi + 4][ni] = __builtin_amdgcn_mfma_f32_16x16x32_bf16(aH[mi][1], bL[ni][1], acc[mi + 4][ni], 0, 0, 0);
            }
        // Q3: aH x bH
        #pragma unroll
        for (int mi = 0; mi < 4; ++mi)
            #pragma unroll
            for (int ni = 0; ni < 2; ++ni) {
                acc[mi + 4][ni + 2] = __builtin_amdgcn_mfma_f32_16x16x32_bf16(aH[mi][0], bH[ni][0], acc[mi + 4][ni + 2], 0, 0, 0);
                acc[mi + 4][ni + 2] = __builtin_amdgcn_mfma_f32_16x16x32_bf16(aH[mi][1], bH[ni][1], acc[mi + 4][ni + 2], 0, 0, 0);
            }
    }
    __syncthreads();

    // ---- epilogue: exp, deterministic sums, bf16 S ----
    float sen2v[4];
    #pragma unroll
    for (int ni = 0; ni < 4; ++ni)
        sen2v[ni] = ws[SEN2_OFF / 4 + colbase + wc * 64 + ni * 16 + c];

    float* red = (float*)&lds[0][0][0];
    // red_rows[4 wc][256], red_cols[2 wr][256]
    float colacc[4] = {0.f, 0.f, 0.f, 0.f};
    #pragma unroll
    for (int mi = 0; mi < 8; ++mi) {
        float ren2v[4], rowacc[4];
        #pragma unroll
        for (int q = 0; q < 4; ++q) {
            ren2v[q] = ws[REN2_OFF / 4 + rowbase + wr * 128 + mi * 16 + g * 4 + q];
            rowacc[q] = 0.f;
        }
        #pragma unroll
        for (int ni = 0; ni < 4; ++ni)
            #pragma unroll
            for (int q = 0; q < 4; ++q) {
                float e = acc[mi][ni][q] - 0.05f * (ren2v[q] + sen2v[ni]) - 1.0f;
                float s = expf(e);
                acc[mi][ni][q] = s;
                rowacc[q] += s;
                colacc[ni] += s;
            }
        #pragma unroll
        for (int q = 0; q < 4; ++q) {
            float v = rowacc[q];
            v += __shfl_xor(v, 1); v += __shfl_xor(v, 2);
            v += __shfl_xor(v, 4); v += __shfl_xor(v, 8);
            if (c == 0) red[wc * 256 + wr * 128 + mi * 16 + g * 4 + q] = v;
        }
    }
    #pragma unroll
    for (int ni = 0; ni < 4; ++ni) {
        float v = colacc[ni];
        v += __shfl_xor(v, 16); v += __shfl_xor(v, 32);
        if (g == 0) red[1024 + wr * 256 + wc * 64 + ni * 16 + c] = v;
    }

    // S as bf16
    #pragma unroll
    for (int mi = 0; mi < 8; ++mi)
        #pragma unroll
        for (int q = 0; q < 4; ++q) {
            int r = rowbase + wr * 128 + mi * 16 + g * 4 + q;
            #pragma unroll
            for (int ni = 0; ni < 4; ++ni) {
                int cc = colbase + wc * 64 + ni * 16 + c;
                S[(size_t)r * Mm + cc] = b16rtn(acc[mi][ni][q]);
            }
        }

    __syncthreads();
    if (tid < 256) {
        float a = red[tid] + red[256 + tid] + red[512 + tid] + red[768 + tid];
        ws[RP16_OFF / 4 + (size_t)(rowbase + tid) * 16 + bx] = a;
    } else {
        int t2 = tid - 256;
        float a = red[1024 + t2] + red[1280 + t2];
        ws[CP16_OFF / 4 + (size_t)(colbase + t2) * 16 + by] = a;
    }
}

__global__ __launch_bounds__(256)
void partred16_kernel(float* __restrict__ w) {
    int i = blockIdx.x * 256 + threadIdx.x;   // [0, 8192)
    const float* p = (i < Nn) ? (w + RP16_OFF / 4 + (size_t)i * 16)
                              : (w + CP16_OFF / 4 + (size_t)(i - Nn) * 16);
    float a = 0.f;
    #pragma unroll
    for (int k = 0; k < 16; ++k) a += p[k];
    if (i < Nn) { w[ROWSUM_OFF / 4 + i] = a; w[RINV_OFF / 4 + i] = 1.0f / a; }
    else        { w[COLSUM_OFF / 4 + i - Nn] = a; w[CINV_OFF / 4 + i - Nn] = 1.0f / a; }
}

// ---------------- selection pipeline (bf16 map + margin + exact rescore) ----------------

__global__ __launch_bounds__(256)
void histb_kernel(const unsigned short* __restrict__ S, float* __restrict__ ws) {
    __shared__ unsigned lh[NBINS];
    for (int b = threadIdx.x; b < NBINS; b += 256) lh[b] = 0;
    __syncthreads();
    const float* rinv = ws + RINV_OFF / 4;
    const float* cinv = ws + CINV_OFF / 4;
    unsigned* hist = (unsigned*)ws + HIST_OFF / 4;
    const uint4* S8 = (const uint4*)S;
    int gtid = blockIdx.x * 256 + threadIdx.x;
    const int total8 = Nn * Mm / 8;
    for (int idx = gtid; idx < total8; idx += gridDim.x * 256) {
        uint4 v = S8[idx];
        int lin = idx * 8;
        int i = lin >> 12, j = lin & 4095;
        float ri = rinv[i];
        float4 c0 = *(const float4*)&cinv[j];
        float4 c1 = *(const float4*)&cinv[j + 4];
        unsigned uu[4] = {v.x, v.y, v.z, v.w};
        float cs[8] = {c0.x, c0.y, c0.z, c0.w, c1.x, c1.y, c1.z, c1.w};
        #pragma unroll
        for (int q = 0; q < 4; ++q) {
            float s0 = __uint_as_float((uu[q] & 0xffffu) << 16);
            float s1 = __uint_as_float((uu[q] >> 16) << 16);
            float f0 = (s0 * ri) * (s0 * cs[q * 2]);
            float f1 = (s1 * ri) * (s1 * cs[q * 2 + 1]);
            atomicAdd(&lh[__float_as_uint(f0) >> 20], 1u);
            atomicAdd(&lh[__float_as_uint(f1) >> 20], 1u);
        }
    }
    __syncthreads();
    for (int b = threadIdx.x; b < NBINS; b += 256) {
        unsigned c = lh[b];
        if (c) atomicAdd(&hist[b], c);
    }
}

__global__ __launch_bounds__(256)
void compactb_kernel(const unsigned short* __restrict__ S, float* __restrict__ ws) {
    __shared__ unsigned lh[NBINS];
    __shared__ unsigned tauS;
    unsigned* ghist = (unsigned*)ws + HIST_OFF / 4;
    int t = threadIdx.x;
    for (int i = t; i < NBINS; i += 256) lh[i] = ghist[NBINS - 1 - i];
    __syncthreads();
    for (int st = 1; st < NBINS; st <<= 1) {
        unsigned tv[16];
        #pragma unroll
        for (int q = 0; q < 16; ++q) {
            int i = q * 256 + t;
            tv[q] = lh[i] + (i >= st ? lh[i - st] : 0u);
        }
        __syncthreads();
        #pragma unroll
        for (int q = 0; q < 16; ++q) lh[q * 256 + t] = tv[q];
        __syncthreads();
    }
    for (int i = t; i < NBINS; i += 256) {
        if (lh[i] >= KOUT && (i == 0 || lh[i - 1] < KOUT))
            tauS = (unsigned)(NBINS - 1 - i) << 20;
    }
    __syncthreads();
    const float tauf = __uint_as_float(tauS) * (1.0f - 1.5e-2f);

    const float* rinv = ws + RINV_OFF / 4;
    const float* cinv = ws + CINV_OFF / 4;
    int* counter = (int*)ws + CNT_OFF / 4;
    float* candv = ws + CANDV_OFF / 4;
    int* candi = (int*)ws + CANDI_OFF / 4;
    const uint4* S8 = (const uint4*)S;
    int gtid = blockIdx.x * 256 + threadIdx.x;
    const int total8 = Nn * Mm / 8;
    for (int idx = gtid; idx < total8; idx += gridDim.x * 256) {
        uint4 v = S8[idx];
        int lin = idx * 8;
        int i = lin >> 12, j = lin & 4095;
        float ri = rinv[i];
        float4 c0 = *(const float4*)&cinv[j];
        float4 c1 = *(const float4*)&cinv[j + 4];
        unsigned uu[4] = {v.x, v.y, v.z, v.w};
        float cs[8] = {c0.x, c0.y, c0.z, c0.w, c1.x, c1.y, c1.z, c1.w};
        #pragma unroll
        for (int q = 0; q < 8; ++q) {
            unsigned hw = (q & 1) ? (uu[q >> 1] >> 16) : (uu[q >> 1] & 0xffffu);
            float s = __uint_as_float(hw << 16);
            float f = (s * ri) * (s * cs[q]);
            if (f >= tauf) {
                int p = atomicAdd(counter, 1);
                if (p < CAP) {
                    candv[p] = f;
                    candi[p] = lin + q;
                }
            }
        }
    }
}

// exact f32 rescore from ORIGINAL inputs + exact sums (one wave per candidate).
__global__ __launch_bounds__(256)
void rescore_kernel(const float* __restrict__ rf, const float* __restrict__ sf,
                    const float* __restrict__ re, const float* __restrict__ se,
                    float* __restrict__ ws) {
    const int* counter = (const int*)ws + CNT_OFF / 4;
    int n = *counter;
    if (n > CAP) n = CAP;
    const int cid = blockIdx.x * 4 + (threadIdx.x >> 6);
    if (cid >= n) return;
    const int lane = threadIdx.x & 63;
    const int idx = ((const int*)ws + CANDI_OFF / 4)[cid];
    const int r = idx >> 12, c = idx & (Mm - 1);
    float d1 = 0.f, d2 = 0.f;
    const float* ar = rf + (size_t)r * Dd;
    const float* bc = sf + (size_t)c * Dd;
    #pragma unroll
    for (int k = 0; k < 8; ++k) d1 = fmaf(ar[lane + k * 64], bc[lane + k * 64], d1);
    const float* er = re + (size_t)r * Ee;
    const float* ec = se + (size_t)c * Ee;
    #pragma unroll
    for (int k = 0; k < 2; ++k) d2 = fmaf(er[lane + k * 64], ec[lane + k * 64], d2);
    #pragma unroll
    for (int o = 32; o > 0; o >>= 1) {
        d1 += __shfl_xor(d1, o);
        d2 += __shfl_xor(d2, o);
    }
    if (lane == 0) {
        float rn = ws[REN2_OFF / 4 + r], cn = ws[SEN2_OFF / 4 + c];
        float e1 = fmaxf(2.0f - 2.0f * d1, 0.0f);
        float e2 = fmaxf(rn + cn - 2.0f * d2, 0.0f);
        float s = expf(-(0.5f * e1 + 0.05f * e2));
        float R = ws[ROWSUM_OFF / 4 + r], C = ws[COLSUM_OFF / 4 + c];
        (ws + CANDV_OFF / 4)[cid] = (s / R) * (s / C);
    }
}

__global__ __launch_bounds__(1024)
void select_kernel(const float* __restrict__ ws, float* __restrict__ out) {
    const int* counter = (const int*)ws + CNT_OFF / 4;
    const float* candv = ws + CANDV_OFF / 4;
    const int* candi = (const int*)ws + CANDI_OFF / 4;
    int n = *counter;
    if (n > CAP) n = CAP;
    int P = 256;
    while (P < n) P <<= 1;
    __shared__ float v[CAP];
    __shared__ int id[CAP];
    int t = threadIdx.x;
    for (int i = t; i < P; i += 1024) {
        if (i < n) { v[i] = candv[i]; id[i] = candi[i]; }
        else       { v[i] = -1.0f;    id[i] = 0x7fffffff; }
    }
    __syncthreads();
    for (int k = 2; k <= P; k <<= 1) {
        for (int j = k >> 1; j > 0; j >>= 1) {
            for (int i = t; i < P; i += 1024) {
                int ixj = i ^ j;
                if (ixj > i) {
                    float va = v[i], vb = v[ixj];
                    int ia = id[i], ib = id[ixj];
                    bool aFirst = (va > vb) || (va == vb && ia < ib);
                    bool up = ((i & k) == 0);
                    if (up ? !aFirst : aFirst) {
                        v[i] = vb; v[ixj] = va;
                        id[i] = ib; id[ixj] = ia;
                    }
                }
            }
            __syncthreads();
        }
    }
    if (t < KOUT) {
        int idx = id[t];
        out[t]            = (float)(idx >> 12);
        out[KOUT + t]     = (float)(idx & (Mm - 1));
        out[2 * KOUT + t] = v[t];
    }
}

// ---------------- old f32 fallback path (proven R2) ----------------

template <int MODE>
__global__ __launch_bounds__(256)
void tile_kernel(const float* __restrict__ rf, const float* __restrict__ sf,
                 const float* __restrict__ re, const float* __restrict__ se,
                 float* __restrict__ ws) {
    const int bx = blockIdx.x, by = blockIdx.y;
    const int tid = threadIdx.x;
    const int tx = tid & 15, ty = tid >> 4;
    const int rowbase = by * 64, colbase = bx * 64;

    __shared__ float As[16][68];
    __shared__ float Bs[16][68];

    float acc1[4][4] = {};
    float acc2[4][4] = {};

    for (int kk = 0; kk < Dd; kk += 16) {
        #pragma unroll
        for (int i = 0; i < 4; ++i) {
            int f = tid + i * 256;
            int r = f >> 4, c = f & 15;
            As[c][r] = rf[(size_t)(rowbase + r) * Dd + kk + c];
            Bs[c][r] = sf[(size_t)(colbase + r) * Dd + kk + c];
        }
        __syncthreads();
        #pragma unroll
        for (int k = 0; k < 16; ++k) {
            float a[4], b[4];
            #pragma unroll
            for (int i = 0; i < 4; ++i) a[i] = As[k][ty * 4 + i];
            #pragma unroll
            for (int j = 0; j < 4; ++j) b[j] = Bs[k][tx * 4 + j];
            #pragma unroll
            for (int i = 0; i < 4; ++i)
                #pragma unroll
                for (int j = 0; j < 4; ++j)
                    acc1[i][j] = fmaf(a[i], b[j], acc1[i][j]);
        }
        __syncthreads();
    }
    for (int kk = 0; kk < Ee; kk += 16) {
        #pragma unroll
        for (int i = 0; i < 4; ++i) {
            int f = tid + i * 256;
            int r = f >> 4, c = f & 15;
            As[c][r] = re[(size_t)(rowbase + r) * Ee + kk + c];
            Bs[c][r] = se[(size_t)(colbase + r) * Ee + kk + c];
        }
        __syncthreads();
        #pragma unroll
        for (int k = 0; k < 16; ++k) {
            float a[4], b[4];
            #pragma unroll
            for (int i = 0; i < 4; ++i) a[i] = As[k][ty * 4 + i];
            #pragma unroll
            for (int j = 0; j < 4; ++j) b[j] = Bs[k][tx * 4 + j];
            #pragma unroll
            for (int i = 0; i < 4; ++i)
                #pragma unroll
                for (int j = 0; j < 4; ++j)
                    acc2[i][j] = fmaf(a[i], b[j], acc2[i][j]);
        }
        __syncthreads();
    }

    const int r0 = rowbase + ty * 4, c0 = colbase + tx * 4;
    float rn[4], cn[4];
    #pragma unroll
    for (int i = 0; i < 4; ++i) rn[i] = ws[REN2_OFF / 4 + r0 + i];
    #pragma unroll
    for (int j = 0; j < 4; ++j) cn[j] = ws[SEN2_OFF / 4 + c0 + j];

    float s[4][4];
    #pragma unroll
    for (int i = 0; i < 4; ++i)
        #pragma unroll
        for (int j = 0; j < 4; ++j) {
            float d1 = fmaxf(2.0f - 2.0f * acc1[i][j], 0.0f);
            float sq = fmaxf(rn[i] + cn[j] - 2.0f * acc2[i][j], 0.0f);
            s[i][j] = expf(-(0.5f * d1 + 0.05f * sq));
        }

    if constexpr (MODE == 0) {
        float* S = ws + S_OFF / 4;
        #pragma unroll
        for (int i = 0; i < 4; ++i) {
            float4 v = make_float4(s[i][0], s[i][1], s[i][2], s[i][3]);
            *(float4*)&S[(size_t)(r0 + i) * Mm + c0] = v;
        }
    }
    if constexpr (MODE == 1) {
        __shared__ float red[64][17];
        #pragma unroll
        for (int i = 0; i < 4; ++i)
            red[ty * 4 + i][tx] = s[i][0] + s[i][1] + s[i][2] + s[i][3];
        __syncthreads();
        if (tid < 64) {
            float t = 0.f;
            #pragma unroll
            for (int k = 0; k < 16; ++k) t += red[tid][k];
            ws[ROWPART_OFF / 4 + (size_t)(rowbase + tid) * 64 + bx] = t;
        }
        __syncthreads();
        #pragma unroll
        for (int j = 0; j < 4; ++j)
            red[tx * 4 + j][ty] = s[0][j] + s[1][j] + s[2][j] + s[3][j];
        __syncthreads();
        if (tid < 64) {
            float t = 0.f;
            #pragma unroll
            for (int k = 0; k < 16; ++k) t += red[tid][k];
            ws[COLPART_OFF / 4 + (size_t)(colbase + tid) * 64 + by] = t;
        }
    }
    if constexpr (MODE == 2) {
        __shared__ unsigned lh[NBINS];
        for (int b = tid; b < NBINS; b += 256) lh[b] = 0;
        __syncthreads();
        float rs[4], cs[4];
        #pragma unroll
        for (int i = 0; i < 4; ++i) rs[i] = ws[ROWSUM_OFF / 4 + r0 + i];
        #pragma unroll
        for (int j = 0; j < 4; ++j) cs[j] = ws[COLSUM_OFF / 4 + c0 + j];
        #pragma unroll
        for (int i = 0; i < 4; ++i)
            #pragma unroll
            for (int j = 0; j < 4; ++j) {
                float f = (s[i][j] / rs[i]) * (s[i][j] / cs[j]);
                atomicAdd(&lh[__float_as_uint(f) >> 20], 1u);
            }
        __syncthreads();
        unsigned* hist = (unsigned*)ws + HIST_OFF / 4;
        for (int b = tid; b < NBINS; b += 256) {
            unsigned cc = lh[b];
            if (cc) atomicAdd(&hist[b], cc);
        }
    }
    if constexpr (MODE == 3) {
        unsigned tau = ((unsigned*)ws)[SCAN_OFF / 4];
        int* counter = (int*)ws + CNT_OFF / 4;
        float* candv = ws + CANDV_OFF / 4;
        int* candi = (int*)ws + CANDI_OFF / 4;
        float rs[4], cs[4];
        #pragma unroll
        for (int i = 0; i < 4; ++i) rs[i] = ws[ROWSUM_OFF / 4 + r0 + i];
        #pragma unroll
        for (int j = 0; j < 4; ++j) cs[j] = ws[COLSUM_OFF / 4 + c0 + j];
        #pragma unroll
        for (int i = 0; i < 4; ++i)
            #pragma unroll
            for (int j = 0; j < 4; ++j) {
                float f = (s[i][j] / rs[i]) * (s[i][j] / cs[j]);
                if (__float_as_uint(f) >= tau) {
                    int p = atomicAdd(counter, 1);
                    if (p < CAP) {
                        candv[p] = f;
                        candi[p] = (r0 + i) * Mm + (c0 + j);
                    }
                }
            }
    }
}

__global__ __launch_bounds__(256)
void partred_kernel(float* __restrict__ w) {
    int i = blockIdx.x * 256 + threadIdx.x;
    const float* rp = w + ROWPART_OFF / 4 + (size_t)i * 64;
    const float* cp = w + COLPART_OFF / 4 + (size_t)i * 64;
    float a = 0.f, b = 0.f;
    #pragma unroll
    for (int k = 0; k < 64; ++k) { a += rp[k]; b += cp[k]; }
    w[ROWSUM_OFF / 4 + i] = a;
    w[COLSUM_OFF / 4 + i] = b;
}

__global__ __launch_bounds__(256)
void rowsum_kernel(const float* __restrict__ S, float* __restrict__ ws) {
    int row = blockIdx.x;
    const float4* p = (const float4*)(S + (size_t)row * Mm);
    float acc = 0.f;
    #pragma unroll
    for (int k = 0; k < 4; ++k) {
        float4 v = p[threadIdx.x + k * 256];
        acc += v.x + v.y + v.z + v.w;
    }
    __shared__ float red[256];
    red[threadIdx.x] = acc;
    __syncthreads();
    for (int o = 128; o > 0; o >>= 1) {
        if (threadIdx.x < o) red[threadIdx.x] += red[threadIdx.x + o];
        __syncthreads();
    }
    if (threadIdx.x == 0) ws[ROWSUM_OFF / 4 + row] = red[0];
}

__global__ __launch_bounds__(256)
void colsum_kernel(const float* __restrict__ S, float* __restrict__ ws) {
    int base = blockIdx.x * 64;
    int c = threadIdx.x & 63, stripe = threadIdx.x >> 6;
    float acc = 0.f;
    for (int r = stripe; r < Nn; r += 4) acc += S[(size_t)r * Mm + base + c];
    __shared__ float red[256];
    red[threadIdx.x] = acc;
    __syncthreads();
    if (threadIdx.x < 64) {
        float t = red[c] + red[c + 64] + red[c + 128] + red[c + 192];
        ws[COLSUM_OFF / 4 + base + c] = t;
    }
}

__global__ __launch_bounds__(256)
void histf_kernel(const float* __restrict__ S, float* __restrict__ ws) {
    __shared__ unsigned lh[NBINS];
    for (int b = threadIdx.x; b < NBINS; b += 256) lh[b] = 0;
    __syncthreads();
    const float* rowsum = ws + ROWSUM_OFF / 4;
    const float* colsum = ws + COLSUM_OFF / 4;
    unsigned* hist = (unsigned*)ws + HIST_OFF / 4;
    const float4* S4 = (const float4*)S;
    int gtid = blockIdx.x * 256 + threadIdx.x;
    const int total4 = Nn * Mm / 4;
    for (int idx = gtid; idx < total4; idx += gridDim.x * 256) {
        float4 v = S4[idx];
        int lin = idx * 4;
        int i = lin >> 12, j = lin & 4095;
        float ri = 1.0f / rowsum[i];
        float4 cv = *(const float4*)&colsum[j];
        float f0 = (v.x * ri) * (v.x / cv.x);
        float f1 = (v.y * ri) * (v.y / cv.y);
        float f2 = (v.z * ri) * (v.z / cv.z);
        float f3 = (v.w * ri) * (v.w / cv.w);
        atomicAdd(&lh[__float_as_uint(f0) >> 20], 1u);
        atomicAdd(&lh[__float_as_uint(f1) >> 20], 1u);
        atomicAdd(&lh[__float_as_uint(f2) >> 20], 1u);
        atomicAdd(&lh[__float_as_uint(f3) >> 20], 1u);
    }
    __syncthreads();
    for (int b = threadIdx.x; b < NBINS; b += 256) {
        unsigned c = lh[b];
        if (c) atomicAdd(&hist[b], c);
    }
}

__global__ __launch_bounds__(256)
void compact_scan_exact_kernel(const float* __restrict__ S, float* __restrict__ ws) {
    __shared__ unsigned lh[NBINS];
    __shared__ unsigned tauS;
    unsigned* ghist = (unsigned*)ws + HIST_OFF / 4;
    int t = threadIdx.x;
    for (int i = t; i < NBINS; i += 256) lh[i] = ghist[NBINS - 1 - i];
    __syncthreads();
    for (int st = 1; st < NBINS; st <<= 1) {
        unsigned tv[16];
        #pragma unroll
        for (int q = 0; q < 16; ++q) {
            int i = q * 256 + t;
            tv[q] = lh[i] + (i >= st ? lh[i - st] : 0u);
        }
        __syncthreads();
        #pragma unroll
        for (int q = 0; q < 16; ++q) lh[q * 256 + t] = tv[q];
        __syncthreads();
    }
    for (int i = t; i < NBINS; i += 256) {
        if (lh[i] >= KOUT && (i == 0 || lh[i - 1] < KOUT))
            tauS = (unsigned)(NBINS - 1 - i) << 20;
    }
    __syncthreads();
    const unsigned tau = tauS;

    const float* rowsum = ws + ROWSUM_OFF / 4;
    const float* colsum = ws + COLSUM_OFF / 4;
    int* counter = (int*)ws + CNT_OFF / 4;
    float* candv = ws + CANDV_OFF / 4;
    int* candi = (int*)ws + CANDI_OFF / 4;
    const float4* S4 = (const float4*)S;
    int gtid = blockIdx.x * 256 + threadIdx.x;
    const int total4 = Nn * Mm / 4;
    for (int idx = gtid; idx < total4; idx += gridDim.x * 256) {
        float4 v = S4[idx];
        int lin = idx * 4;
        int i = lin >> 12, j = lin & 4095;
        float ri = 1.0f / rowsum[i];
        float4 cv = *(const float4*)&colsum[j];
        float f[4] = {(v.x * ri) * (v.x / cv.x), (v.y * ri) * (v.y / cv.y),
                      (v.z * ri) * (v.z / cv.z), (v.w * ri) * (v.w / cv.w)};
        #pragma unroll
        for (int q = 0; q < 4; ++q) {
            if (__float_as_uint(f[q]) >= tau) {
                int p = atomicAdd(counter, 1);
                if (p < CAP) {
                    candv[p] = f[q];
                    candi[p] = lin + q;
                }
            }
        }
    }
}

__global__ __launch_bounds__(1024)
void scan_kernel(float* __restrict__ ws) {
    unsigned* hist = (unsigned*)ws + HIST_OFF / 4;
    unsigned* scano = (unsigned*)ws + SCAN_OFF / 4;
    __shared__ unsigned A[NBINS], B[NBINS];
    int t = threadIdx.x;
    for (int i = t; i < NBINS; i += 1024) A[i] = hist[NBINS - 1 - i];
    __syncthreads();
    unsigned* src = A;
    unsigned* dst = B;
    for (int st = 1; st < NBINS; st <<= 1) {
        for (int i = t; i < NBINS; i += 1024)
            dst[i] = src[i] + (i >= st ? src[i - st] : 0u);
        __syncthreads();
        unsigned* tmp = src; src = dst; dst = tmp;
    }
    for (int i = t; i < NBINS; i += 1024) {
        if (src[i] >= KOUT && (i == 0 || src[i - 1] < KOUT)) {
            scano[0] = (unsigned)(NBINS - 1 - i) << 20;
            scano[1] = src[i];
        }
    }
}

extern "C" void kernel_launch(void* const* d_in, const int* in_sizes, int n_in,
                              void* d_out, int out_size, void* d_ws, size_t ws_size,
                              hipStream_t stream) {
    const float* rf = (const float*)d_in[0];
    const float* sf = (const float*)d_in[1];
    const float* re = (const float*)d_in[2];
    const float* se = (const float*)d_in[3];
    float* ws = (float*)d_ws;
    float* out = (float*)d_out;

    if (ws_size >= NEW_REQ) {
        unsigned short* AH = (unsigned short*)((char*)d_ws + AH_OFF);
        unsigned short* AL = (unsigned short*)((char*)d_ws + AL_OFF);
        unsigned short* BH = (unsigned short*)((char*)d_ws + BH_OFF);
        unsigned short* BL = (unsigned short*)((char*)d_ws + BL_OFF);
        unsigned short* S = (unsigned short*)((char*)d_ws + SNEW_OFF);
        prep_kernel<<<640, 256, 0, stream>>>(rf, sf, re, se, AH, AL, BH, BL, ws);
        mfma_gemm_kernel<<<dim3(16, 16), 512, 0, stream>>>(
            (const __bf16*)AH, (const __bf16*)AL, (const __bf16*)BH, (const __bf16*)BL, ws, S);
        partred16_kernel<<<32, 256, 0, stream>>>(ws);
        histb_kernel<<<1024, 256, 0, stream>>>(S, ws);
        compactb_kernel<<<1024, 256, 0, stream>>>(S, ws);
        rescore_kernel<<<1024, 256, 0, stream>>>(rf, sf, re, se, ws);
        select_kernel<<<1, 1024, 0, stream>>>(ws, out);
    } else if (ws_size >= FAST_REQ) {
        float* S = ws + S_OFF / 4;
        dim3 tgrid(Mm / 64, Nn / 64);
        setup_kernel<<<Nn + Mm, 64, 0, stream>>>(re, se, ws);
        tile_kernel<0><<<tgrid, 256, 0, stream>>>(rf, sf, re, se, ws);
        rowsum_kernel<<<Nn, 256, 0, stream>>>(S, ws);
        colsum_kernel<<<Mm / 64, 256, 0, stream>>>(S, ws);
        histf_kernel<<<1024, 256, 0, stream>>>(S, ws);
        compact_scan_exact_kernel<<<1024, 256, 0, stream>>>(S, ws);
        select_kernel<<<1, 1024, 0, stream>>>(ws, out);
    } else {
        dim3 tgrid(Mm / 64, Nn / 64);
        setup_kernel<<<Nn + Mm, 64, 0, stream>>>(re, se, ws);
        tile_kernel<1><<<tgrid, 256, 0, stream>>>(rf, sf, re, se, ws);
        partred_kernel<<<16, 256, 0, stream>>>(ws);
        tile_kernel<2><<<tgrid, 256, 0, stream>>>(rf, sf, re, se, ws);
        scan_kernel<<<1, 1024, 0, stream>>>(ws);
        tile_kernel<3><<<tgrid, 256, 0, stream>>>(rf, sf, re, se, ws);
        select_kernel<<<1, 1024, 0, stream>>>(ws, out);
    }
}